// Round 3
// baseline (2476.419 us; speedup 1.0000x reference)
//
#include <hip/hip_runtime.h>

// ---------------- problem constants ----------------
constexpr int cB  = 2;
constexpr int cNR = 16384;
constexpr int cNP = 65536;
constexpr int cE  = 262144;
constexpr int cF  = 128;
#define EB 16   // edges (or nodes) per block

// ws float offsets — per-batch-chunked: agg/cnt sized [NP], reused across b.
// Footprint: 32MB agg + 256KB cnt + 6KB ss  (~32.3 MB)
constexpr size_t WS_AGG = 0;                              // [NP,128] f32 segment sums
constexpr size_t WS_CNT = (size_t)cNP * cF;               // [NP] f32 counts
constexpr size_t WS_SS  = WS_CNT + (size_t)cNP;           // 3 sets x [B,256] scale/shift

// ---------------- helpers ----------------
__device__ __forceinline__ float swishf(float x) { return x / (1.0f + expf(-x)); }

// x transposed in LDS: xT[k][row]; W row-major [K][128]; thread t = out channel
template <int K>
__device__ __forceinline__ void gemm_tile(const float (*xT)[EB],
                                          const float* __restrict__ W,
                                          const float* __restrict__ bias,
                                          float* acc, int t) {
  float bb = bias[t];
#pragma unroll
  for (int ee = 0; ee < EB; ++ee) acc[ee] = bb;
  const float* __restrict__ Wp = W + t;
#pragma unroll 4
  for (int k = 0; k < K; ++k) {
    float w = Wp[k * cF];
    const float* xr = xT[k];
#pragma unroll
    for (int ee = 0; ee < EB; ++ee) acc[ee] = fmaf(xr[ee], w, acc[ee]);
  }
}

// conditioned LayerNorm over 128 channels for EB rows (private LDS scratch)
__device__ __forceinline__ void cond_norm_block(float* acc, float (*nsc)[EB],
                                                float (*red)[EB][8], float (*musig)[2],
                                                const float* __restrict__ ssp, int t) {
  __syncthreads();
#pragma unroll
  for (int ee = 0; ee < EB; ++ee) nsc[t][ee] = acc[ee];
  __syncthreads();
  {
    int ee = t & 15, part = t >> 4;      // 8 partials x 16 rows
    float s = 0.f, q = 0.f;
#pragma unroll
    for (int i = 0; i < 16; ++i) { float v = nsc[part * 16 + i][ee]; s += v; q += v * v; }
    red[0][ee][part] = s; red[1][ee][part] = q;
  }
  __syncthreads();
  if (t < EB) {
    float s = 0.f, q = 0.f;
#pragma unroll
    for (int p = 0; p < 8; ++p) { s += red[0][t][p]; q += red[1][t][p]; }
    float mu  = s * (1.0f / 128.0f);
    float var = fmaxf(q * (1.0f / 128.0f) - mu * mu, 0.0f);
    musig[t][0] = mu;
    musig[t][1] = rsqrtf(var + 1e-6f);
  }
  __syncthreads();
  float scale = ssp[t], shift = ssp[128 + t];
#pragma unroll
  for (int ee = 0; ee < EB; ++ee)
    acc[ee] = (acc[ee] - musig[ee][0]) * musig[ee][1] * (1.0f + scale) + shift;
}

// ---------------- kernel 0: zero agg + cnt ----------------
__global__ void zero_kernel(float4* __restrict__ p, int n4) {
  int i = blockIdx.x * 256 + threadIdx.x;
  if (i < n4) p[i] = make_float4(0.f, 0.f, 0.f, 0.f);
}

// ---------------- kernel 1: tau-conditioned scale/shift (3 sets) ----------------
__global__ void cond_kernel(const float* __restrict__ tau,
                            const float* __restrict__ Ce1, const float* __restrict__ ce1,
                            const float* __restrict__ Ce2, const float* __restrict__ ce2,
                            const float* __restrict__ Cu1, const float* __restrict__ cu1,
                            const float* __restrict__ Cu2, const float* __restrict__ cu2,
                            const float* __restrict__ Cp1, const float* __restrict__ cp1,
                            const float* __restrict__ Cp2, const float* __restrict__ cp2,
                            float* __restrict__ ss) {
  int set = blockIdx.x, b = blockIdx.y, j = threadIdx.x;
  const float *C1, *c1, *C2, *c2;
  if (set == 0)      { C1 = Ce1; c1 = ce1; C2 = Ce2; c2 = ce2; }
  else if (set == 1) { C1 = Cu1; c1 = cu1; C2 = Cu2; c2 = cu2; }
  else               { C1 = Cp1; c1 = cp1; C2 = Cp2; c2 = cp2; }
  float tf = tau[b];
  float a = c2[j];
  for (int k = 0; k < 16; ++k) {
    float h = swishf(tf * C1[k] + c1[k]);
    a = fmaf(h, C2[k * 256 + j], a);
  }
  ss[(size_t)set * cB * 256 + (size_t)b * 256 + j] = a;
}

// ---------------- edge-weight bundle ----------------
struct EW { const float *We1, *be1, *We2, *be2, *Wu1, *bu1, *Wu2, *bu2; };
struct PW { const float *Wp1, *bp1, *Wp2, *bp2, *Wo1, *bo1, *Wo2, *bo2; };

// ---------------- kernel 2: fused edge pipeline + segment-sum atomics (one batch) --------
__global__ __launch_bounds__(128) void edge_kernel(
    const float* __restrict__ rnode, const float* __restrict__ pnode,
    const float* __restrict__ efeat, const int* __restrict__ senders,
    const int* __restrict__ receivers, EW w,
    const float* __restrict__ ss, float* __restrict__ agg, float* __restrict__ cnt, int b) {
  const int e0 = blockIdx.x * EB;
  const int t  = threadIdx.x;  // channel 0..127

  __shared__ __align__(16) float xcat[3 * cF][EB];  // [e_embed | sf | rf], transposed
  __shared__ __align__(16) float hT[cF][EB];
  __shared__ __align__(16) float nsc[cF][EB];
  __shared__ float eefs[EB][4];
  __shared__ float red[2][EB][8];
  __shared__ float musig[EB][2];
  __shared__ int sidx[EB], ridx[EB];

  if (t < EB) {
    sidx[t] = min(max(senders[(size_t)b * cE + e0 + t], 0), cNR - 1);
    ridx[t] = min(max(receivers[(size_t)b * cE + e0 + t], 0), cNP - 1);
  } else if (t >= 64 && t < 64 + EB * 4) {
    int q = t - 64;
    eefs[q >> 2][q & 3] = efeat[((size_t)b * cE + e0 + (q >> 2)) * 4 + (q & 3)];
  }
  __syncthreads();

  // gather sender (rnode) / receiver (pnode) rows — 512B coalesced row reads
  for (int ee = 0; ee < EB; ++ee) {
    xcat[cF + t][ee]     = rnode[((size_t)b * cNR + sidx[ee]) * cF + t];
    xcat[2 * cF + t][ee] = pnode[((size_t)b * cNP + ridx[ee]) * cF + t];
  }

  float acc[EB], e0r[EB];

  // embed layer 1: swish(ef @ We1 + be1), K=4
  {
    float bb = w.be1[t];
#pragma unroll
    for (int ee = 0; ee < EB; ++ee) acc[ee] = bb;
#pragma unroll
    for (int k = 0; k < 4; ++k) {
      float wv = w.We1[k * cF + t];
#pragma unroll
      for (int ee = 0; ee < EB; ++ee) acc[ee] = fmaf(eefs[ee][k], wv, acc[ee]);
    }
#pragma unroll
    for (int ee = 0; ee < EB; ++ee) hT[t][ee] = swishf(acc[ee]);
  }
  __syncthreads();

  // embed layer 2 + cond-norm -> e_embed
  gemm_tile<cF>(hT, w.We2, w.be2, acc, t);
  cond_norm_block(acc, nsc, red, musig, ss + (size_t)b * 256, t);  // set 0

#pragma unroll
  for (int ee = 0; ee < EB; ++ee) { e0r[ee] = acc[ee]; xcat[t][ee] = acc[ee]; }
  __syncthreads();

  // update layer 1: K=384 over [e|sf|rf]
  gemm_tile<3 * cF>(xcat, w.Wu1, w.bu1, acc, t);
  __syncthreads();
#pragma unroll
  for (int ee = 0; ee < EB; ++ee) hT[t][ee] = swishf(acc[ee]);
  __syncthreads();

  // update layer 2 + cond-norm
  gemm_tile<cF>(hT, w.Wu2, w.bu2, acc, t);
  cond_norm_block(acc, nsc, red, musig, ss + (size_t)cB * 256 + (size_t)b * 256, t);  // set 1

  // e = e_embed + u ; segment-sum atomics
#pragma unroll
  for (int ee = 0; ee < EB; ++ee)
    atomicAdd(&agg[(size_t)ridx[ee] * cF + t], e0r[ee] + acc[ee]);
  if (t == 0) {
    for (int ee = 0; ee < EB; ++ee) atomicAdd(&cnt[ridx[ee]], 1.0f);
  }
}

// ---------------- kernel 3: fused pnode update + output MLP (one batch) ----------------
__global__ __launch_bounds__(128) void pnode_kernel(
    const float* __restrict__ pnode, PW w,
    const float* __restrict__ ss, const float* __restrict__ agg,
    const float* __restrict__ cnt, float* __restrict__ out, int b) {
  const int n0 = blockIdx.x * EB;
  const int t  = threadIdx.x;

  __shared__ __align__(16) float xin[2 * cF][EB];
  __shared__ __align__(16) float hT[cF][EB];
  __shared__ __align__(16) float nsc[cF][EB];
  __shared__ float red[2][EB][8];
  __shared__ float musig[EB][2];
  __shared__ float cinv[EB];

  if (t < EB) cinv[t] = 1.0f / fmaxf(cnt[n0 + t], 1.0f);
  __syncthreads();

  float acc[EB], pfr[EB];
  for (int ee = 0; ee < EB; ++ee) {
    float pf = pnode[((size_t)b * cNP + n0 + ee) * cF + t];
    pfr[ee] = pf;
    xin[t][ee]      = pf;
    xin[cF + t][ee] = agg[(size_t)(n0 + ee) * cF + t] * cinv[ee];  // segment mean
  }
  __syncthreads();

  // pnode MLP layer 1: K=256
  gemm_tile<2 * cF>(xin, w.Wp1, w.bp1, acc, t);
  __syncthreads();
#pragma unroll
  for (int ee = 0; ee < EB; ++ee) hT[t][ee] = swishf(acc[ee]);
  __syncthreads();

  // pnode MLP layer 2 + cond-norm, residual
  gemm_tile<cF>(hT, w.Wp2, w.bp2, acc, t);
  cond_norm_block(acc, nsc, red, musig, ss + 2 * (size_t)cB * 256 + (size_t)b * 256, t);  // set 2
  __syncthreads();
#pragma unroll
  for (int ee = 0; ee < EB; ++ee) { acc[ee] += pfr[ee]; xin[t][ee] = acc[ee]; }
  __syncthreads();

  // output layer 1: K=128
  gemm_tile<cF>(xin, w.Wo1, w.bo1, acc, t);
  __syncthreads();
#pragma unroll
  for (int ee = 0; ee < EB; ++ee) hT[t][ee] = swishf(acc[ee]);
  __syncthreads();

  // output layer 2: K=128, N=4
  if (t < 64) {
    int ee = t >> 2, oc = t & 3;
    float a = w.bo2[oc];
    for (int k = 0; k < cF; ++k) a = fmaf(hT[k][ee], w.Wo2[k * 4 + oc], a);
    out[((size_t)b * cNP + n0 + ee) * 4 + oc] = a;
  }
}

// ---------------- launch ----------------
extern "C" void kernel_launch(void* const* d_in, const int* in_sizes, int n_in,
                              void* d_out, int out_size, void* d_ws, size_t ws_size,
                              hipStream_t stream) {
  const float* rnode = (const float*)d_in[0];
  const float* pnode = (const float*)d_in[1];
  const float* efeat = (const float*)d_in[2];
  const float* tau   = (const float*)d_in[3];
  const int* senders   = (const int*)d_in[40];
  const int* receivers = (const int*)d_in[41];
  float* ws = (float*)d_ws;

  EW ew = { (const float*)d_in[4],  (const float*)d_in[6],   // We1, be1
            (const float*)d_in[5],  (const float*)d_in[7],   // We2, be2
            (const float*)d_in[12], (const float*)d_in[14],  // Wu1, bu1
            (const float*)d_in[13], (const float*)d_in[15] };// Wu2, bu2
  PW pw = { (const float*)d_in[20], (const float*)d_in[22],  // Wp1, bp1
            (const float*)d_in[21], (const float*)d_in[23],  // Wp2, bp2
            (const float*)d_in[36], (const float*)d_in[38],  // Wo1, bo1
            (const float*)d_in[37], (const float*)d_in[39] };// Wo2, bo2

  cond_kernel<<<dim3(3, cB), 256, 0, stream>>>(
      tau,
      (const float*)d_in[8],  (const float*)d_in[10],
      (const float*)d_in[9],  (const float*)d_in[11],
      (const float*)d_in[16], (const float*)d_in[18],
      (const float*)d_in[17], (const float*)d_in[19],
      (const float*)d_in[24], (const float*)d_in[26],
      (const float*)d_in[25], (const float*)d_in[27],
      ws + WS_SS);

  // per-batch chunking keeps ws footprint ~32.3 MB (agg is [NP,F], reused)
  const int n4 = (int)(WS_SS / 4);  // agg+cnt exactly divisible by 4
  for (int b = 0; b < cB; ++b) {
    zero_kernel<<<(n4 + 255) / 256, 256, 0, stream>>>((float4*)ws, n4);
    edge_kernel<<<cE / EB, 128, 0, stream>>>(
        rnode, pnode, efeat, senders, receivers, ew,
        ws + WS_SS, ws + WS_AGG, ws + WS_CNT, b);
    pnode_kernel<<<cNP / EB, 128, 0, stream>>>(
        pnode, pw, ws + WS_SS, ws + WS_AGG, ws + WS_CNT,
        (float*)d_out, b);
  }
}

// Round 4
// 1094.869 us; speedup vs baseline: 2.2618x; 2.2618x over previous
//
#include <hip/hip_runtime.h>

// ---------------- problem constants ----------------
constexpr int cB  = 2;
constexpr int cNR = 16384;
constexpr int cNP = 65536;
constexpr int cE  = 262144;
constexpr int cF  = 128;
constexpr int SP  = 136;   // bf16 row stride in LDS (2-way bank aliasing = free)

typedef unsigned short u16;
using f32x4 = __attribute__((ext_vector_type(4))) float;
using s8v   = __attribute__((ext_vector_type(8))) short;

// ws float offsets
constexpr size_t WS_AGG = 0;                        // [NP][128] f32 segment sums
constexpr size_t WS_CNT = (size_t)cNP * cF;         // [NP] counts
constexpr size_t WS_SS  = WS_CNT + cNP;             // 3 sets x [B,256]
constexpr size_t WS_WB  = WS_SS + 3 * cB * 256;     // swizzled bf16 weights (144 k8-blocks x 1024 u16)

// swizzled-weight segment bases (units of k8 = 8 K-rows)
constexpr int G8_We2 = 0, G8_Wu1 = 16, G8_Wu2 = 64, G8_Wp1 = 80, G8_Wp2 = 112, G8_Wo1 = 128;
constexpr int G8_TOT = 144;

// ---------------- helpers ----------------
__device__ __forceinline__ float bf2f(u16 u) {
  union { unsigned int i; float f; } v; v.i = ((unsigned int)u) << 16; return v.f;
}
__device__ __forceinline__ u16 f2bf(float f) {
  union { float f; unsigned int i; } v; v.f = f;
  unsigned int x = v.i;
  return (u16)((x + 0x7fffu + ((x >> 16) & 1u)) >> 16);
}
__device__ __forceinline__ unsigned pack2(float a, float b) {
  return (unsigned)f2bf(a) | ((unsigned)f2bf(b) << 16);
}
__device__ __forceinline__ float swishf(float x) { return x / (1.0f + expf(-x)); }

// stage one 16-k8 weight chunk (32 KB) global->LDS; caller barriers
__device__ __forceinline__ void stage_wb(u16* wbuf, const u16* wbg, int t) {
#pragma unroll
  for (int i = 0; i < 8; ++i)
    ((uint4*)wbuf)[t + i * 256] = ((const uint4*)wbg)[t + i * 256];
}

// K=128 MFMA pass: act = bf16 [128][SP], wbuf = swizzled [16 k8][128][8]
__device__ __forceinline__ void kloop128(const u16* act, const u16* wbuf,
                                         f32x4 (&acc)[4][4], int r0, int c0, int l16, int quad) {
#pragma unroll
  for (int k0 = 0; k0 < 4; ++k0) {
    s8v af[4], bf[4];
#pragma unroll
    for (int ri = 0; ri < 4; ++ri)
      af[ri] = *(const s8v*)(act + (size_t)(r0 + ri * 16 + l16) * SP + k0 * 32 + quad * 8);
#pragma unroll
    for (int ci = 0; ci < 4; ++ci)
      bf[ci] = *(const s8v*)(wbuf + ((size_t)(k0 * 4 + quad) * 128 + c0 + ci * 16 + l16) * 8);
#pragma unroll
    for (int ri = 0; ri < 4; ++ri)
#pragma unroll
      for (int ci = 0; ci < 4; ++ci)
        acc[ri][ci] = __builtin_amdgcn_mfma_f32_16x16x32_bf16(af[ri], bf[ci], acc[ri][ci], 0, 0, 0);
  }
}

__device__ __forceinline__ void init_acc(f32x4 (&acc)[4][4], const float* __restrict__ bias,
                                         int c0, int l16) {
#pragma unroll
  for (int ci = 0; ci < 4; ++ci) {
    float bv = bias[c0 + ci * 16 + l16];
#pragma unroll
    for (int ri = 0; ri < 4; ++ri) acc[ri][ci] = (f32x4){bv, bv, bv, bv};
  }
}

// conditioned LayerNorm on MFMA C-layout (col=lane&15, row=quad*4+reg within 16-tile)
__device__ __forceinline__ void cond_norm_mfma(f32x4 (&acc)[4][4], float* red, float* musig,
                                               const float* __restrict__ ssp,
                                               int r0, int c0, int l16, int quad, int wv, int t) {
  __syncthreads();                 // protect red/musig reuse; all waves done reading A
  int wc = (wv >> 1) * 2;
#pragma unroll
  for (int ri = 0; ri < 4; ++ri)
#pragma unroll
    for (int reg = 0; reg < 4; ++reg) {
      float v0 = acc[ri][0][reg], v1 = acc[ri][1][reg], v2 = acc[ri][2][reg], v3 = acc[ri][3][reg];
      float s = v0 + v1 + v2 + v3;
      float q = v0 * v0 + v1 * v1 + v2 * v2 + v3 * v3;
      s += __shfl_xor(s, 1); q += __shfl_xor(q, 1);
      s += __shfl_xor(s, 2); q += __shfl_xor(q, 2);
      s += __shfl_xor(s, 4); q += __shfl_xor(q, 4);
      s += __shfl_xor(s, 8); q += __shfl_xor(q, 8);
      if (l16 == 0) {
        int row = r0 + ri * 16 + quad * 4 + reg;
        red[row * 4 + wc]     = s;
        red[row * 4 + wc + 1] = q;
      }
    }
  __syncthreads();
  if (t < 128) {
    float sum = red[t * 4 + 0] + red[t * 4 + 2];
    float sq  = red[t * 4 + 1] + red[t * 4 + 3];
    float mu  = sum * (1.0f / 128.0f);
    float var = fmaxf(sq * (1.0f / 128.0f) - mu * mu, 0.0f);
    musig[t * 2]     = mu;
    musig[t * 2 + 1] = rsqrtf(var + 1e-6f);
  }
  __syncthreads();
  float scl[4], shf[4];
#pragma unroll
  for (int ci = 0; ci < 4; ++ci) {
    int col = c0 + ci * 16 + l16;
    scl[ci] = 1.0f + ssp[col];
    shf[ci] = ssp[128 + col];
  }
#pragma unroll
  for (int ri = 0; ri < 4; ++ri)
#pragma unroll
    for (int reg = 0; reg < 4; ++reg) {
      int row = r0 + ri * 16 + quad * 4 + reg;
      float mu = musig[row * 2], is = musig[row * 2 + 1];
#pragma unroll
      for (int ci = 0; ci < 4; ++ci)
        acc[ri][ci][reg] = (acc[ri][ci][reg] - mu) * is * scl[ci] + shf[ci];
    }
}

template <bool DOSWISH>
__device__ __forceinline__ void store_bf16(u16* buf, const f32x4 (&acc)[4][4],
                                           int r0, int c0, int l16, int quad) {
#pragma unroll
  for (int ri = 0; ri < 4; ++ri)
#pragma unroll
    for (int reg = 0; reg < 4; ++reg) {
      int row = r0 + ri * 16 + quad * 4 + reg;
#pragma unroll
      for (int ci = 0; ci < 4; ++ci) {
        float v = acc[ri][ci][reg];
        if (DOSWISH) v = swishf(v);
        buf[(size_t)row * SP + c0 + ci * 16 + l16] = f2bf(v);
      }
    }
}

// ---------------- kernel: zero agg + cnt ----------------
__global__ void zero_kernel(float4* __restrict__ p, int n4) {
  int i = blockIdx.x * 256 + threadIdx.x;
  if (i < n4) p[i] = make_float4(0.f, 0.f, 0.f, 0.f);
}

// ---------------- kernel: weight bf16 swizzle  W[K][128] -> [K/8][128][8] ----------------
struct SwzSrc { const float* p[6]; };  // We2, Wu1, Wu2, Wp1, Wp2, Wo1

__global__ void swz_kernel(SwzSrc s, u16* __restrict__ wb) {
  int t = blockIdx.x * 256 + threadIdx.x;
  if (t >= G8_TOT * 128) return;
  int n = t & 127, g8 = t >> 7;
  int seg, base;
  if (g8 < G8_Wu1)      { seg = 0; base = G8_We2; }
  else if (g8 < G8_Wu2) { seg = 1; base = G8_Wu1; }
  else if (g8 < G8_Wp1) { seg = 2; base = G8_Wu2; }
  else if (g8 < G8_Wp2) { seg = 3; base = G8_Wp1; }
  else if (g8 < G8_Wo1) { seg = 4; base = G8_Wp2; }
  else                  { seg = 5; base = G8_Wo1; }
  const float* W = s.p[seg];
  int k8l = g8 - base;
  u16 v[8];
#pragma unroll
  for (int j = 0; j < 8; ++j) v[j] = f2bf(W[(size_t)(k8l * 8 + j) * 128 + n]);
  ((uint4*)wb)[g8 * 128 + n] = *(uint4*)v;
}

// ---------------- kernel: tau-conditioned scale/shift (3 sets) ----------------
__global__ void cond_kernel(const float* __restrict__ tau,
                            const float* __restrict__ Ce1, const float* __restrict__ ce1,
                            const float* __restrict__ Ce2, const float* __restrict__ ce2,
                            const float* __restrict__ Cu1, const float* __restrict__ cu1,
                            const float* __restrict__ Cu2, const float* __restrict__ cu2,
                            const float* __restrict__ Cp1, const float* __restrict__ cp1,
                            const float* __restrict__ Cp2, const float* __restrict__ cp2,
                            float* __restrict__ ss) {
  int set = blockIdx.x, b = blockIdx.y, j = threadIdx.x;
  const float *C1, *c1, *C2, *c2;
  if (set == 0)      { C1 = Ce1; c1 = ce1; C2 = Ce2; c2 = ce2; }
  else if (set == 1) { C1 = Cu1; c1 = cu1; C2 = Cu2; c2 = cu2; }
  else               { C1 = Cp1; c1 = cp1; C2 = Cp2; c2 = cp2; }
  float tf = tau[b];
  float a = c2[j];
  for (int k = 0; k < 16; ++k) {
    float h = swishf(tf * C1[k] + c1[k]);
    a = fmaf(h, C2[k * 256 + j], a);
  }
  ss[(size_t)set * cB * 256 + (size_t)b * 256 + j] = a;
}

// ---------------- fused MFMA edge pipeline (one batch), M=128 edges/block ----------------
struct EWb { const float *We1, *be1, *be2, *bu1, *bu2; };

struct __align__(16) EdgeSmem {
  u16 bufE[128 * SP];   // h_embed -> e_emb
  u16 bufS[128 * SP];   // sf -> h2
  u16 bufR[128 * SP];   // rf
  u16 wbuf[16384];      // 32 KB staged weights
  float ef4[512];
  float red[512];
  float musig[256];
  int sidx[128], ridx[128];
};

__global__ __launch_bounds__(256, 1) void edge_mfma(
    const float* __restrict__ rnode, const float* __restrict__ pnode,
    const float* __restrict__ efeat, const int* __restrict__ senders,
    const int* __restrict__ receivers, EWb w, const u16* __restrict__ wb,
    const float* __restrict__ ss, float* __restrict__ agg, float* __restrict__ cnt, int b) {
  __shared__ EdgeSmem sm;
  const int t = threadIdx.x, wv = t >> 6, lane = t & 63, l16 = lane & 15, quad = lane >> 4;
  const int r0 = (wv & 1) * 64, c0 = (wv >> 1) * 64;
  const int e0 = blockIdx.x * 128;

  if (t < 128) {
    sm.sidx[t] = min(max(senders[(size_t)b * cE + e0 + t], 0), cNR - 1);
    sm.ridx[t] = min(max(receivers[(size_t)b * cE + e0 + t], 0), cNP - 1);
  }
  ((float2*)sm.ef4)[t] = ((const float2*)(efeat + ((size_t)b * cE + e0) * 4))[t];
  __syncthreads();

  // gather sender/receiver rows -> bf16 LDS
  for (int rr = 0; rr < 32; ++rr) {
    int row = wv * 32 + rr;
    float2 sv = *(const float2*)(rnode + ((size_t)b * cNR + sm.sidx[row]) * cF + lane * 2);
    float2 rv = *(const float2*)(pnode + ((size_t)b * cNP + sm.ridx[row]) * cF + lane * 2);
    *(unsigned*)(sm.bufS + (size_t)row * SP + lane * 2) = pack2(sv.x, sv.y);
    *(unsigned*)(sm.bufR + (size_t)row * SP + lane * 2) = pack2(rv.x, rv.y);
  }

  // embed layer 1 (K=4, VALU) -> bufE
  {
    int col = t & 127, half = t >> 7;
    float w0 = w.We1[col], w1 = w.We1[128 + col], w2 = w.We1[256 + col], w3 = w.We1[384 + col];
    float bb = w.be1[col];
    for (int r = 0; r < 64; ++r) {
      int row = half * 64 + r;
      float a = fmaf(sm.ef4[row * 4 + 3], w3, fmaf(sm.ef4[row * 4 + 2], w2,
                fmaf(sm.ef4[row * 4 + 1], w1, fmaf(sm.ef4[row * 4 + 0], w0, bb))));
      sm.bufE[(size_t)row * SP + col] = f2bf(swishf(a));
    }
  }
  __syncthreads();

  f32x4 acc[4][4];

  // ---- embed L2 + cond-norm(set0) -> e_emb (bufE) ----
  stage_wb(sm.wbuf, wb + (size_t)G8_We2 * 1024, t);
  __syncthreads();
  init_acc(acc, w.be2, c0, l16);
  kloop128(sm.bufE, sm.wbuf, acc, r0, c0, l16, quad);
  cond_norm_mfma(acc, sm.red, sm.musig, ss + (size_t)b * 256, r0, c0, l16, quad, wv, t);
  __syncthreads();
  store_bf16<false>(sm.bufE, acc, r0, c0, l16, quad);

  // ---- update L1: K=384 over [e|sf|rf] -> h2 (bufS) ----
  __syncthreads();
  stage_wb(sm.wbuf, wb + (size_t)G8_Wu1 * 1024, t);
  __syncthreads();
  init_acc(acc, w.bu1, c0, l16);
  kloop128(sm.bufE, sm.wbuf, acc, r0, c0, l16, quad);
  __syncthreads();
  stage_wb(sm.wbuf, wb + (size_t)(G8_Wu1 + 16) * 1024, t);
  __syncthreads();
  kloop128(sm.bufS, sm.wbuf, acc, r0, c0, l16, quad);
  __syncthreads();
  stage_wb(sm.wbuf, wb + (size_t)(G8_Wu1 + 32) * 1024, t);
  __syncthreads();
  kloop128(sm.bufR, sm.wbuf, acc, r0, c0, l16, quad);
  __syncthreads();
  store_bf16<true>(sm.bufS, acc, r0, c0, l16, quad);

  // ---- update L2 + cond-norm(set1) ----
  __syncthreads();
  stage_wb(sm.wbuf, wb + (size_t)G8_Wu2 * 1024, t);
  __syncthreads();
  init_acc(acc, w.bu2, c0, l16);
  kloop128(sm.bufS, sm.wbuf, acc, r0, c0, l16, quad);
  cond_norm_mfma(acc, sm.red, sm.musig, ss + (size_t)(cB + b) * 256, r0, c0, l16, quad, wv, t);

  // e = e_emb + u ; segment-sum atomics
#pragma unroll
  for (int ri = 0; ri < 4; ++ri)
#pragma unroll
    for (int reg = 0; reg < 4; ++reg) {
      int row = r0 + ri * 16 + quad * 4 + reg;
      size_t rbase = (size_t)sm.ridx[row] * cF;
#pragma unroll
      for (int ci = 0; ci < 4; ++ci) {
        int col = c0 + ci * 16 + l16;
        float v = acc[ri][ci][reg] + bf2f(sm.bufE[(size_t)row * SP + col]);
        atomicAdd(agg + rbase + col, v);
      }
    }
  if (t < 128) atomicAdd(cnt + sm.ridx[t], 1.0f);
}

// ---------------- fused MFMA pnode pipeline (one batch), M=128 nodes/block ----------------
struct PWb { const float *bp1, *bp2, *bo1, *Wo2, *bo2; };

struct __align__(16) PnodeSmem {
  u16 bufP[128 * SP];
  u16 bufA[128 * SP];
  u16 bufH[128 * SP];
  u16 wbuf[16384];
  float red[512];
  float musig[256];
  float cinv[128];
};

__global__ __launch_bounds__(256, 1) void pnode_mfma(
    const float* __restrict__ pnode, PWb w, const u16* __restrict__ wb,
    const float* __restrict__ ss, const float* __restrict__ agg,
    const float* __restrict__ cnt, float* __restrict__ out, int b) {
  __shared__ PnodeSmem sm;
  const int t = threadIdx.x, wv = t >> 6, lane = t & 63, l16 = lane & 15, quad = lane >> 4;
  const int r0 = (wv & 1) * 64, c0 = (wv >> 1) * 64;
  const int n0 = blockIdx.x * 128;

  if (t < 128) sm.cinv[t] = 1.0f / fmaxf(cnt[n0 + t], 1.0f);
  __syncthreads();

  for (int rr = 0; rr < 32; ++rr) {
    int row = wv * 32 + rr;
    float2 pv = *(const float2*)(pnode + ((size_t)b * cNP + n0 + row) * cF + lane * 2);
    float2 av = *(const float2*)(agg + (size_t)(n0 + row) * cF + lane * 2);
    float ci_ = sm.cinv[row];
    *(unsigned*)(sm.bufP + (size_t)row * SP + lane * 2) = pack2(pv.x, pv.y);
    *(unsigned*)(sm.bufA + (size_t)row * SP + lane * 2) = pack2(av.x * ci_, av.y * ci_);
  }
  __syncthreads();

  f32x4 acc[4][4];

  // ---- pnode L1: K=256 over [pf|mean] -> bufH ----
  stage_wb(sm.wbuf, wb + (size_t)G8_Wp1 * 1024, t);
  __syncthreads();
  init_acc(acc, w.bp1, c0, l16);
  kloop128(sm.bufP, sm.wbuf, acc, r0, c0, l16, quad);
  __syncthreads();
  stage_wb(sm.wbuf, wb + (size_t)(G8_Wp1 + 16) * 1024, t);
  __syncthreads();
  kloop128(sm.bufA, sm.wbuf, acc, r0, c0, l16, quad);
  __syncthreads();
  store_bf16<true>(sm.bufH, acc, r0, c0, l16, quad);

  // ---- pnode L2 + cond-norm(set2) + residual -> bufP ----
  __syncthreads();
  stage_wb(sm.wbuf, wb + (size_t)G8_Wp2 * 1024, t);
  __syncthreads();
  init_acc(acc, w.bp2, c0, l16);
  kloop128(sm.bufH, sm.wbuf, acc, r0, c0, l16, quad);
  cond_norm_mfma(acc, sm.red, sm.musig, ss + (size_t)(2 * cB + b) * 256, r0, c0, l16, quad, wv, t);
#pragma unroll
  for (int ri = 0; ri < 4; ++ri)
#pragma unroll
    for (int reg = 0; reg < 4; ++reg) {
      int row = r0 + ri * 16 + quad * 4 + reg;
#pragma unroll
      for (int ci = 0; ci < 4; ++ci)
        acc[ri][ci][reg] += bf2f(sm.bufP[(size_t)row * SP + c0 + ci * 16 + l16]);
    }
  __syncthreads();
  store_bf16<false>(sm.bufP, acc, r0, c0, l16, quad);

  // ---- output L1: K=128 -> bufH ----
  __syncthreads();
  stage_wb(sm.wbuf, wb + (size_t)G8_Wo1 * 1024, t);
  __syncthreads();
  init_acc(acc, w.bo1, c0, l16);
  kloop128(sm.bufP, sm.wbuf, acc, r0, c0, l16, quad);
  __syncthreads();
  store_bf16<true>(sm.bufH, acc, r0, c0, l16, quad);
  __syncthreads();

  // ---- output L2: K=128, N=4 (VALU) ----
  {
    int row = t >> 1, oc = (t & 1) * 2;
    float a0 = w.bo2[oc], a1 = w.bo2[oc + 1];
    for (int k = 0; k < cF; ++k) {
      float h = bf2f(sm.bufH[(size_t)row * SP + k]);
      a0 = fmaf(h, w.Wo2[k * 4 + oc], a0);
      a1 = fmaf(h, w.Wo2[k * 4 + oc + 1], a1);
    }
    size_t o = ((size_t)b * cNP + n0 + row) * 4 + oc;
    out[o] = a0;
    out[o + 1] = a1;
  }
}

// ---------------- launch ----------------
extern "C" void kernel_launch(void* const* d_in, const int* in_sizes, int n_in,
                              void* d_out, int out_size, void* d_ws, size_t ws_size,
                              hipStream_t stream) {
  const float* rnode = (const float*)d_in[0];
  const float* pnode = (const float*)d_in[1];
  const float* efeat = (const float*)d_in[2];
  const float* tau   = (const float*)d_in[3];
  const int* senders   = (const int*)d_in[40];
  const int* receivers = (const int*)d_in[41];
  float* ws = (float*)d_ws;
  u16* wb = (u16*)(ws + WS_WB);

  // weight swizzle (bf16, MFMA-B layout)
  SwzSrc sw;
  sw.p[0] = (const float*)d_in[5];   // We2
  sw.p[1] = (const float*)d_in[12];  // Wu1
  sw.p[2] = (const float*)d_in[13];  // Wu2
  sw.p[3] = (const float*)d_in[20];  // Wp1
  sw.p[4] = (const float*)d_in[21];  // Wp2
  sw.p[5] = (const float*)d_in[36];  // Wo1
  swz_kernel<<<(G8_TOT * 128 + 255) / 256, 256, 0, stream>>>(sw, wb);

  cond_kernel<<<dim3(3, cB), 256, 0, stream>>>(
      tau,
      (const float*)d_in[8],  (const float*)d_in[10],
      (const float*)d_in[9],  (const float*)d_in[11],
      (const float*)d_in[16], (const float*)d_in[18],
      (const float*)d_in[17], (const float*)d_in[19],
      (const float*)d_in[24], (const float*)d_in[26],
      (const float*)d_in[25], (const float*)d_in[27],
      ws + WS_SS);

  EWb ew = { (const float*)d_in[4], (const float*)d_in[6], (const float*)d_in[7],
             (const float*)d_in[14], (const float*)d_in[15] };   // We1, be1, be2, bu1, bu2
  PWb pw = { (const float*)d_in[22], (const float*)d_in[23], (const float*)d_in[38],
             (const float*)d_in[37], (const float*)d_in[39] };   // bp1, bp2, bo1, Wo2, bo2

  const int n4 = (int)(WS_SS / 4);  // agg+cnt in float4 units
  for (int b = 0; b < cB; ++b) {
    zero_kernel<<<(n4 + 255) / 256, 256, 0, stream>>>((float4*)ws, n4);
    edge_mfma<<<cE / 128, 256, 0, stream>>>(
        rnode, pnode, efeat, senders, receivers, ew, wb,
        ws + WS_SS, ws + WS_AGG, ws + WS_CNT, b);
    pnode_mfma<<<cNP / 128, 256, 0, stream>>>(
        pnode, pw, wb, ws + WS_SS, ws + WS_AGG, ws + WS_CNT,
        (float*)d_out, b);
  }
}

// Round 5
// 829.602 us; speedup vs baseline: 2.9851x; 1.3198x over previous
//
#include <hip/hip_runtime.h>

// ---------------- problem constants ----------------
constexpr int cB  = 2;
constexpr int cNR = 16384;
constexpr int cNP = 65536;
constexpr int cE  = 262144;
constexpr int cF  = 128;
constexpr int SP  = 136;   // bf16 row stride in LDS (2-way bank aliasing = free)

typedef unsigned short u16;
using f32x4 = __attribute__((ext_vector_type(4))) float;
using s8v   = __attribute__((ext_vector_type(8))) short;

// ws float offsets
constexpr size_t WS_AGG = 0;                        // [NP][128] f32 segment sums
constexpr size_t WS_CNT = (size_t)cNP * cF;         // [NP] counts
constexpr size_t WS_SS  = WS_CNT + cNP;             // 3 sets x [B,256]
constexpr size_t WS_WB  = WS_SS + 3 * cB * 256;     // swizzled bf16 weights

// swizzled-weight segment bases (units of k8 = 8 K-rows; one k8 = 1024 u16)
constexpr int G8_We2 = 0, G8_Wu1 = 16, G8_Wu2 = 64, G8_Wp1 = 80, G8_Wp2 = 112, G8_Wo1 = 128;
constexpr int G8_TOT = 144;

// ---------------- helpers ----------------
__device__ __forceinline__ float bf2f(u16 u) {
  union { unsigned int i; float f; } v; v.i = ((unsigned int)u) << 16; return v.f;
}
__device__ __forceinline__ u16 f2bf(float f) {
  union { float f; unsigned int i; } v; v.f = f;
  unsigned int x = v.i;
  return (u16)((x + 0x7fffu + ((x >> 16) & 1u)) >> 16);
}
__device__ __forceinline__ unsigned pack2(float a, float b) {
  return (unsigned)f2bf(a) | ((unsigned)f2bf(b) << 16);
}
__device__ __forceinline__ float swishf(float x) { return x / (1.0f + expf(-x)); }

// K=128 MFMA pass, M=64 tile: act = bf16 LDS [64][SP]; weights straight from
// global (L2-resident, swizzled [k8][128][8]) into registers — no LDS staging.
__device__ __forceinline__ void kloop128g(const u16* act, const u16* __restrict__ wbg,
                                          f32x4 (&acc)[2][4], int r0, int c0, int l16, int quad) {
  s8v bf[4][4];
#pragma unroll
  for (int k0 = 0; k0 < 4; ++k0)
#pragma unroll
    for (int ci = 0; ci < 4; ++ci)
      bf[k0][ci] = *(const s8v*)(wbg + ((size_t)(k0 * 4 + quad) * 128 + c0 + ci * 16 + l16) * 8);
#pragma unroll
  for (int k0 = 0; k0 < 4; ++k0) {
    s8v af[2];
#pragma unroll
    for (int ri = 0; ri < 2; ++ri)
      af[ri] = *(const s8v*)(act + (size_t)(r0 + ri * 16 + l16) * SP + k0 * 32 + quad * 8);
#pragma unroll
    for (int ri = 0; ri < 2; ++ri)
#pragma unroll
      for (int ci = 0; ci < 4; ++ci)
        acc[ri][ci] = __builtin_amdgcn_mfma_f32_16x16x32_bf16(af[ri], bf[k0][ci], acc[ri][ci], 0, 0, 0);
  }
}

__device__ __forceinline__ void init_acc(f32x4 (&acc)[2][4], const float* __restrict__ bias,
                                         int c0, int l16) {
#pragma unroll
  for (int ci = 0; ci < 4; ++ci) {
    float bv = bias[c0 + ci * 16 + l16];
#pragma unroll
    for (int ri = 0; ri < 2; ++ri) acc[ri][ci] = (f32x4){bv, bv, bv, bv};
  }
}

// conditioned LayerNorm on MFMA C-layout, M=64 (wave covers 32 rows x 64 cols)
__device__ __forceinline__ void cond_norm_mfma(f32x4 (&acc)[2][4], float* red, float* musig,
                                               const float* __restrict__ ssp,
                                               int r0, int c0, int l16, int quad, int wv, int t) {
  __syncthreads();                 // all waves done with prior LDS reads; red/musig reuse safe
  int wc = (wv >> 1) * 2;          // column-half slot
#pragma unroll
  for (int ri = 0; ri < 2; ++ri)
#pragma unroll
    for (int reg = 0; reg < 4; ++reg) {
      float v0 = acc[ri][0][reg], v1 = acc[ri][1][reg], v2 = acc[ri][2][reg], v3 = acc[ri][3][reg];
      float s = v0 + v1 + v2 + v3;
      float q = v0 * v0 + v1 * v1 + v2 * v2 + v3 * v3;
      s += __shfl_xor(s, 1); q += __shfl_xor(q, 1);
      s += __shfl_xor(s, 2); q += __shfl_xor(q, 2);
      s += __shfl_xor(s, 4); q += __shfl_xor(q, 4);
      s += __shfl_xor(s, 8); q += __shfl_xor(q, 8);
      if (l16 == 0) {
        int row = r0 + ri * 16 + quad * 4 + reg;
        red[row * 4 + wc]     = s;
        red[row * 4 + wc + 1] = q;
      }
    }
  __syncthreads();
  if (t < 64) {
    float sum = red[t * 4 + 0] + red[t * 4 + 2];
    float sq  = red[t * 4 + 1] + red[t * 4 + 3];
    float mu  = sum * (1.0f / 128.0f);
    float var = fmaxf(sq * (1.0f / 128.0f) - mu * mu, 0.0f);
    musig[t * 2]     = mu;
    musig[t * 2 + 1] = rsqrtf(var + 1e-6f);
  }
  __syncthreads();
  float scl[4], shf[4];
#pragma unroll
  for (int ci = 0; ci < 4; ++ci) {
    int col = c0 + ci * 16 + l16;
    scl[ci] = 1.0f + ssp[col];
    shf[ci] = ssp[128 + col];
  }
#pragma unroll
  for (int ri = 0; ri < 2; ++ri)
#pragma unroll
    for (int reg = 0; reg < 4; ++reg) {
      int row = r0 + ri * 16 + quad * 4 + reg;
      float mu = musig[row * 2], is = musig[row * 2 + 1];
#pragma unroll
      for (int ci = 0; ci < 4; ++ci)
        acc[ri][ci][reg] = (acc[ri][ci][reg] - mu) * is * scl[ci] + shf[ci];
    }
}

template <bool DOSWISH>
__device__ __forceinline__ void store_bf16(u16* buf, const f32x4 (&acc)[2][4],
                                           int r0, int c0, int l16, int quad) {
#pragma unroll
  for (int ri = 0; ri < 2; ++ri)
#pragma unroll
    for (int reg = 0; reg < 4; ++reg) {
      int row = r0 + ri * 16 + quad * 4 + reg;
#pragma unroll
      for (int ci = 0; ci < 4; ++ci) {
        float v = acc[ri][ci][reg];
        if (DOSWISH) v = swishf(v);
        buf[(size_t)row * SP + c0 + ci * 16 + l16] = f2bf(v);
      }
    }
}

// ---------------- kernel: zero agg + cnt ----------------
__global__ void zero_kernel(float4* __restrict__ p, int n4) {
  int i = blockIdx.x * 256 + threadIdx.x;
  if (i < n4) p[i] = make_float4(0.f, 0.f, 0.f, 0.f);
}

// ---------------- kernel: weight bf16 swizzle  W[K][128] -> [K/8][128][8] ----------------
struct SwzSrc { const float* p[6]; };  // We2, Wu1, Wu2, Wp1, Wp2, Wo1

__global__ void swz_kernel(SwzSrc s, u16* __restrict__ wb) {
  int t = blockIdx.x * 256 + threadIdx.x;
  if (t >= G8_TOT * 128) return;
  int n = t & 127, g8 = t >> 7;
  int seg, base;
  if (g8 < G8_Wu1)      { seg = 0; base = G8_We2; }
  else if (g8 < G8_Wu2) { seg = 1; base = G8_Wu1; }
  else if (g8 < G8_Wp1) { seg = 2; base = G8_Wu2; }
  else if (g8 < G8_Wp2) { seg = 3; base = G8_Wp1; }
  else if (g8 < G8_Wo1) { seg = 4; base = G8_Wp2; }
  else                  { seg = 5; base = G8_Wo1; }
  const float* W = s.p[seg];
  int k8l = g8 - base;
  u16 v[8];
#pragma unroll
  for (int j = 0; j < 8; ++j) v[j] = f2bf(W[(size_t)(k8l * 8 + j) * 128 + n]);
  ((uint4*)wb)[g8 * 128 + n] = *(uint4*)v;
}

// ---------------- kernel: tau-conditioned scale/shift (3 sets) ----------------
__global__ void cond_kernel(const float* __restrict__ tau,
                            const float* __restrict__ Ce1, const float* __restrict__ ce1,
                            const float* __restrict__ Ce2, const float* __restrict__ ce2,
                            const float* __restrict__ Cu1, const float* __restrict__ cu1,
                            const float* __restrict__ Cu2, const float* __restrict__ cu2,
                            const float* __restrict__ Cp1, const float* __restrict__ cp1,
                            const float* __restrict__ Cp2, const float* __restrict__ cp2,
                            float* __restrict__ ss) {
  int set = blockIdx.x, b = blockIdx.y, j = threadIdx.x;
  const float *C1, *c1, *C2, *c2;
  if (set == 0)      { C1 = Ce1; c1 = ce1; C2 = Ce2; c2 = ce2; }
  else if (set == 1) { C1 = Cu1; c1 = cu1; C2 = Cu2; c2 = cu2; }
  else               { C1 = Cp1; c1 = cp1; C2 = Cp2; c2 = cp2; }
  float tf = tau[b];
  float a = c2[j];
  for (int k = 0; k < 16; ++k) {
    float h = swishf(tf * C1[k] + c1[k]);
    a = fmaf(h, C2[k * 256 + j], a);
  }
  ss[(size_t)set * cB * 256 + (size_t)b * 256 + j] = a;
}

// ---------------- fused MFMA edge pipeline (one batch), M=64 edges/block ----------------
struct EWb { const float *We1, *be1, *be2, *bu1, *bu2; };

struct __align__(16) EdgeSmem {
  u16 bufE[64 * SP];   // h_embed -> e_emb
  u16 bufS[64 * SP];   // sf -> h2
  u16 bufR[64 * SP];   // rf
  float ef4[256];
  float red[256];
  float musig[128];
  int sidx[64], ridx[64];
};  // ~55.3 KB -> 2 blocks/CU

__global__ __launch_bounds__(256, 2) void edge_mfma(
    const float* __restrict__ rnode, const float* __restrict__ pnode,
    const float* __restrict__ efeat, const int* __restrict__ senders,
    const int* __restrict__ receivers, EWb w, const u16* __restrict__ wb,
    const float* __restrict__ ss, float* __restrict__ agg, float* __restrict__ cnt, int b) {
  __shared__ EdgeSmem sm;
  const int t = threadIdx.x, wv = t >> 6, lane = t & 63, l16 = lane & 15, quad = lane >> 4;
  const int r0 = (wv & 1) * 32, c0 = (wv >> 1) * 64;
  const int e0 = blockIdx.x * 64;

  if (t < 64) {
    sm.sidx[t] = min(max(senders[(size_t)b * cE + e0 + t], 0), cNR - 1);
    sm.ridx[t] = min(max(receivers[(size_t)b * cE + e0 + t], 0), cNP - 1);
  } else if (t >= 128) {
    ((float2*)sm.ef4)[t - 128] = ((const float2*)(efeat + ((size_t)b * cE + e0) * 4))[t - 128];
  }
  __syncthreads();  // b1

  // gather sender/receiver rows -> bf16 LDS (16 rows per wave)
  for (int rr = 0; rr < 16; ++rr) {
    int row = wv * 16 + rr;
    float2 sv = *(const float2*)(rnode + ((size_t)b * cNR + sm.sidx[row]) * cF + lane * 2);
    float2 rv = *(const float2*)(pnode + ((size_t)b * cNP + sm.ridx[row]) * cF + lane * 2);
    *(unsigned*)(sm.bufS + (size_t)row * SP + lane * 2) = pack2(sv.x, sv.y);
    *(unsigned*)(sm.bufR + (size_t)row * SP + lane * 2) = pack2(rv.x, rv.y);
  }

  // embed layer 1 (K=4, VALU) -> bufE
  {
    int col = t & 127, half = t >> 7;
    float w0 = w.We1[col], w1 = w.We1[128 + col], w2 = w.We1[256 + col], w3 = w.We1[384 + col];
    float bb = w.be1[col];
    for (int r = 0; r < 32; ++r) {
      int row = half * 32 + r;
      float a = fmaf(sm.ef4[row * 4 + 3], w3, fmaf(sm.ef4[row * 4 + 2], w2,
                fmaf(sm.ef4[row * 4 + 1], w1, fmaf(sm.ef4[row * 4 + 0], w0, bb))));
      sm.bufE[(size_t)row * SP + col] = f2bf(swishf(a));
    }
  }
  __syncthreads();  // b2: bufE/S/R visible

  f32x4 acc[2][4];

  // ---- embed L2 + cond-norm(set0) -> e_emb (bufE) ----
  init_acc(acc, w.be2, c0, l16);
  kloop128g(sm.bufE, wb + (size_t)G8_We2 * 1024, acc, r0, c0, l16, quad);
  cond_norm_mfma(acc, sm.red, sm.musig, ss + (size_t)b * 256, r0, c0, l16, quad, wv, t);
  store_bf16<false>(sm.bufE, acc, r0, c0, l16, quad);
  __syncthreads();  // b3: e_emb visible

  // ---- update L1: K=384 over [e|sf|rf] ----
  init_acc(acc, w.bu1, c0, l16);
  kloop128g(sm.bufE, wb + (size_t)G8_Wu1 * 1024, acc, r0, c0, l16, quad);
  kloop128g(sm.bufS, wb + (size_t)(G8_Wu1 + 16) * 1024, acc, r0, c0, l16, quad);
  kloop128g(sm.bufR, wb + (size_t)(G8_Wu1 + 32) * 1024, acc, r0, c0, l16, quad);
  __syncthreads();  // b4: all waves done reading bufS
  store_bf16<true>(sm.bufS, acc, r0, c0, l16, quad);
  __syncthreads();  // b5: h2 visible

  // ---- update L2 + cond-norm(set1) ----
  init_acc(acc, w.bu2, c0, l16);
  kloop128g(sm.bufS, wb + (size_t)G8_Wu2 * 1024, acc, r0, c0, l16, quad);
  cond_norm_mfma(acc, sm.red, sm.musig, ss + (size_t)(cB + b) * 256, r0, c0, l16, quad, wv, t);

  // e = e_emb + u ; segment-sum atomics
#pragma unroll
  for (int ri = 0; ri < 2; ++ri)
#pragma unroll
    for (int reg = 0; reg < 4; ++reg) {
      int row = r0 + ri * 16 + quad * 4 + reg;
      size_t rbase = (size_t)sm.ridx[row] * cF;
#pragma unroll
      for (int ci = 0; ci < 4; ++ci) {
        int col = c0 + ci * 16 + l16;
        float v = acc[ri][ci][reg] + bf2f(sm.bufE[(size_t)row * SP + col]);
        atomicAdd(agg + rbase + col, v);
      }
    }
  if (t < 64) atomicAdd(cnt + sm.ridx[t], 1.0f);
}

// ---------------- fused MFMA pnode pipeline (one batch), M=64 nodes/block ----------------
struct PWb { const float *bp1, *bp2, *bo1, *Wo2, *bo2; };

struct __align__(16) PnodeSmem {
  u16 bufP[64 * SP];
  u16 bufA[64 * SP];
  u16 bufH[64 * SP];
  float red[256];
  float musig[128];
  float cinv[64];
};  // ~54 KB -> 2 blocks/CU

__global__ __launch_bounds__(256, 2) void pnode_mfma(
    const float* __restrict__ pnode, PWb w, const u16* __restrict__ wb,
    const float* __restrict__ ss, const float* __restrict__ agg,
    const float* __restrict__ cnt, float* __restrict__ out, int b) {
  __shared__ PnodeSmem sm;
  const int t = threadIdx.x, wv = t >> 6, lane = t & 63, l16 = lane & 15, quad = lane >> 4;
  const int r0 = (wv & 1) * 32, c0 = (wv >> 1) * 64;
  const int n0 = blockIdx.x * 64;

  if (t < 64) sm.cinv[t] = 1.0f / fmaxf(cnt[n0 + t], 1.0f);
  __syncthreads();  // b1

  for (int rr = 0; rr < 16; ++rr) {
    int row = wv * 16 + rr;
    float2 pv = *(const float2*)(pnode + ((size_t)b * cNP + n0 + row) * cF + lane * 2);
    float2 av = *(const float2*)(agg + (size_t)(n0 + row) * cF + lane * 2);
    float ci_ = sm.cinv[row];
    *(unsigned*)(sm.bufP + (size_t)row * SP + lane * 2) = pack2(pv.x, pv.y);
    *(unsigned*)(sm.bufA + (size_t)row * SP + lane * 2) = pack2(av.x * ci_, av.y * ci_);
  }
  __syncthreads();  // b2

  f32x4 acc[2][4];

  // ---- pnode L1: K=256 over [pf|mean] -> bufH ----
  init_acc(acc, w.bp1, c0, l16);
  kloop128g(sm.bufP, wb + (size_t)G8_Wp1 * 1024, acc, r0, c0, l16, quad);
  kloop128g(sm.bufA, wb + (size_t)(G8_Wp1 + 16) * 1024, acc, r0, c0, l16, quad);
  store_bf16<true>(sm.bufH, acc, r0, c0, l16, quad);  // no prior readers of bufH
  __syncthreads();  // b3: bufH visible

  // ---- pnode L2 + cond-norm(set2) + residual -> bufP ----
  init_acc(acc, w.bp2, c0, l16);
  kloop128g(sm.bufH, wb + (size_t)G8_Wp2 * 1024, acc, r0, c0, l16, quad);
  cond_norm_mfma(acc, sm.red, sm.musig, ss + (size_t)(2 * cB + b) * 256, r0, c0, l16, quad, wv, t);
#pragma unroll
  for (int ri = 0; ri < 2; ++ri)
#pragma unroll
    for (int reg = 0; reg < 4; ++reg) {
      int row = r0 + ri * 16 + quad * 4 + reg;
#pragma unroll
      for (int ci = 0; ci < 4; ++ci)
        acc[ri][ci][reg] += bf2f(sm.bufP[(size_t)row * SP + c0 + ci * 16 + l16]);
    }
  __syncthreads();  // b4: all waves done reading bufP
  store_bf16<false>(sm.bufP, acc, r0, c0, l16, quad);
  __syncthreads();  // b5: p_new visible

  // ---- output L1: K=128 -> bufH ----
  init_acc(acc, w.bo1, c0, l16);
  kloop128g(sm.bufP, wb + (size_t)G8_Wo1 * 1024, acc, r0, c0, l16, quad);
  __syncthreads();  // b6: all waves done reading bufH (from Wp2 kloop) — safe to overwrite
  store_bf16<true>(sm.bufH, acc, r0, c0, l16, quad);
  __syncthreads();  // b7: bufH(h_out) visible

  // ---- output L2: K=128, N=4 (VALU, one output per thread) ----
  {
    int row = t >> 2, oc = t & 3;
    float w0 = w.Wo2 ? 0.f : 0.f;  // (placeholder to keep compiler quiet about unused)
    (void)w0;
    float a = w.bo2[oc];
    for (int k8 = 0; k8 < 16; ++k8) {
      s8v hv = *(const s8v*)(sm.bufH + (size_t)row * SP + k8 * 8);
#pragma unroll
      for (int j = 0; j < 8; ++j)
        a = fmaf(bf2f((u16)hv[j]), w.Wo2[(k8 * 8 + j) * 4 + oc], a);
    }
    out[((size_t)b * cNP + n0 + row) * 4 + oc] = a;
  }
}

// ---------------- launch ----------------
extern "C" void kernel_launch(void* const* d_in, const int* in_sizes, int n_in,
                              void* d_out, int out_size, void* d_ws, size_t ws_size,
                              hipStream_t stream) {
  const float* rnode = (const float*)d_in[0];
  const float* pnode = (const float*)d_in[1];
  const float* efeat = (const float*)d_in[2];
  const float* tau   = (const float*)d_in[3];
  const int* senders   = (const int*)d_in[40];
  const int* receivers = (const int*)d_in[41];
  float* ws = (float*)d_ws;
  u16* wb = (u16*)(ws + WS_WB);

  SwzSrc sw;
  sw.p[0] = (const float*)d_in[5];   // We2
  sw.p[1] = (const float*)d_in[12];  // Wu1
  sw.p[2] = (const float*)d_in[13];  // Wu2
  sw.p[3] = (const float*)d_in[20];  // Wp1
  sw.p[4] = (const float*)d_in[21];  // Wp2
  sw.p[5] = (const float*)d_in[36];  // Wo1
  swz_kernel<<<(G8_TOT * 128 + 255) / 256, 256, 0, stream>>>(sw, wb);

  cond_kernel<<<dim3(3, cB), 256, 0, stream>>>(
      tau,
      (const float*)d_in[8],  (const float*)d_in[10],
      (const float*)d_in[9],  (const float*)d_in[11],
      (const float*)d_in[16], (const float*)d_in[18],
      (const float*)d_in[17], (const float*)d_in[19],
      (const float*)d_in[24], (const float*)d_in[26],
      (const float*)d_in[25], (const float*)d_in[27],
      ws + WS_SS);

  EWb ew = { (const float*)d_in[4], (const float*)d_in[6], (const float*)d_in[7],
             (const float*)d_in[14], (const float*)d_in[15] };   // We1, be1, be2, bu1, bu2
  PWb pw = { (const float*)d_in[22], (const float*)d_in[23], (const float*)d_in[38],
             (const float*)d_in[37], (const float*)d_in[39] };   // bp1, bp2, bo1, Wo2, bo2

  const int n4 = (int)(WS_SS / 4);
  for (int b = 0; b < cB; ++b) {
    zero_kernel<<<(n4 + 255) / 256, 256, 0, stream>>>((float4*)ws, n4);
    edge_mfma<<<cE / 64, 256, 0, stream>>>(
        rnode, pnode, efeat, senders, receivers, ew, wb,
        ws + WS_SS, ws + WS_AGG, ws + WS_CNT, b);
    pnode_mfma<<<cNP / 64, 256, 0, stream>>>(
        pnode, pw, wb, ws + WS_SS, ws + WS_AGG, ws + WS_CNT,
        (float*)d_out, b);
  }
}

// Round 6
// 740.358 us; speedup vs baseline: 3.3449x; 1.1205x over previous
//
#include <hip/hip_runtime.h>

// ---------------- problem constants ----------------
constexpr int cB  = 2;
constexpr int cNR = 16384;
constexpr int cNP = 65536;
constexpr int cE  = 262144;
constexpr int cF  = 128;
constexpr int SP  = 136;   // bf16 row stride in LDS (2-way bank aliasing = free)

typedef unsigned short u16;
using f32x4 = __attribute__((ext_vector_type(4))) float;
using s8v   = __attribute__((ext_vector_type(8))) short;

// ws float offsets
constexpr size_t WS_AGG = 0;                        // [NP][128] f32 segment sums
constexpr size_t WS_CNT = (size_t)cNP * cF;         // [NP] counts
constexpr size_t WS_SS  = WS_CNT + cNP;             // 3 sets x [B,256]
constexpr size_t WS_WB  = WS_SS + 3 * cB * 256;     // swizzled bf16 weights

// swizzled-weight segment bases (units of k8 = 8 K-rows; one k8 = 1024 u16)
constexpr int G8_We2 = 0, G8_Wu1 = 16, G8_Wu2 = 64, G8_Wp1 = 80, G8_Wp2 = 112, G8_Wo1 = 128;
constexpr int G8_TOT = 144;

// ---------------- helpers ----------------
__device__ __forceinline__ float bf2f(u16 u) {
  union { unsigned int i; float f; } v; v.i = ((unsigned int)u) << 16; return v.f;
}
__device__ __forceinline__ u16 f2bf(float f) {
  union { float f; unsigned int i; } v; v.f = f;
  unsigned int x = v.i;
  return (u16)((x + 0x7fffu + ((x >> 16) & 1u)) >> 16);
}
__device__ __forceinline__ unsigned pack2(float a, float b) {
  return (unsigned)f2bf(a) | ((unsigned)f2bf(b) << 16);
}
__device__ __forceinline__ float swishf(float x) { return x / (1.0f + __expf(-x)); }

// K=128 MFMA pass, M=64 tile: act = bf16 LDS [64][SP]; weights straight from
// global (L2-resident, swizzled [k8][128][8]) into registers.
__device__ __forceinline__ void kloop128g(const u16* act, const u16* __restrict__ wbg,
                                          f32x4 (&acc)[2][4], int r0, int c0, int l16, int quad) {
  s8v bf[4][4];
#pragma unroll
  for (int k0 = 0; k0 < 4; ++k0)
#pragma unroll
    for (int ci = 0; ci < 4; ++ci)
      bf[k0][ci] = *(const s8v*)(wbg + ((size_t)(k0 * 4 + quad) * 128 + c0 + ci * 16 + l16) * 8);
#pragma unroll
  for (int k0 = 0; k0 < 4; ++k0) {
    s8v af[2];
#pragma unroll
    for (int ri = 0; ri < 2; ++ri)
      af[ri] = *(const s8v*)(act + (size_t)(r0 + ri * 16 + l16) * SP + k0 * 32 + quad * 8);
#pragma unroll
    for (int ri = 0; ri < 2; ++ri)
#pragma unroll
      for (int ci = 0; ci < 4; ++ci)
        acc[ri][ci] = __builtin_amdgcn_mfma_f32_16x16x32_bf16(af[ri], bf[k0][ci], acc[ri][ci], 0, 0, 0);
  }
}

__device__ __forceinline__ void init_acc(f32x4 (&acc)[2][4], const float* __restrict__ bias,
                                         int c0, int l16) {
#pragma unroll
  for (int ci = 0; ci < 4; ++ci) {
    float bv = bias[c0 + ci * 16 + l16];
#pragma unroll
    for (int ri = 0; ri < 2; ++ri) acc[ri][ci] = (f32x4){bv, bv, bv, bv};
  }
}

// conditioned LayerNorm on MFMA C-layout, M=64 (wave covers 32 rows x 64 cols)
__device__ __forceinline__ void cond_norm_mfma(f32x4 (&acc)[2][4], float* red, float* musig,
                                               const float* __restrict__ ssp,
                                               int r0, int c0, int l16, int quad, int wv, int t) {
  __syncthreads();                 // all waves past their kloop LDS reads; red/musig reuse safe
  int wc = (wv >> 1) * 2;          // column-half slot
#pragma unroll
  for (int ri = 0; ri < 2; ++ri)
#pragma unroll
    for (int reg = 0; reg < 4; ++reg) {
      float v0 = acc[ri][0][reg], v1 = acc[ri][1][reg], v2 = acc[ri][2][reg], v3 = acc[ri][3][reg];
      float s = v0 + v1 + v2 + v3;
      float q = v0 * v0 + v1 * v1 + v2 * v2 + v3 * v3;
      s += __shfl_xor(s, 1); q += __shfl_xor(q, 1);
      s += __shfl_xor(s, 2); q += __shfl_xor(q, 2);
      s += __shfl_xor(s, 4); q += __shfl_xor(q, 4);
      s += __shfl_xor(s, 8); q += __shfl_xor(q, 8);
      if (l16 == 0) {
        int row = r0 + ri * 16 + quad * 4 + reg;
        red[row * 4 + wc]     = s;
        red[row * 4 + wc + 1] = q;
      }
    }
  __syncthreads();
  if (t < 64) {
    float sum = red[t * 4 + 0] + red[t * 4 + 2];
    float sq  = red[t * 4 + 1] + red[t * 4 + 3];
    float mu  = sum * (1.0f / 128.0f);
    float var = fmaxf(sq * (1.0f / 128.0f) - mu * mu, 0.0f);
    musig[t * 2]     = mu;
    musig[t * 2 + 1] = rsqrtf(var + 1e-6f);
  }
  __syncthreads();
  float scl[4], shf[4];
#pragma unroll
  for (int ci = 0; ci < 4; ++ci) {
    int col = c0 + ci * 16 + l16;
    scl[ci] = 1.0f + ssp[col];
    shf[ci] = ssp[128 + col];
  }
#pragma unroll
  for (int ri = 0; ri < 2; ++ri)
#pragma unroll
    for (int reg = 0; reg < 4; ++reg) {
      int row = r0 + ri * 16 + quad * 4 + reg;
      float mu = musig[row * 2], is = musig[row * 2 + 1];
#pragma unroll
      for (int ci = 0; ci < 4; ++ci)
        acc[ri][ci][reg] = (acc[ri][ci][reg] - mu) * is * scl[ci] + shf[ci];
    }
}

template <bool DOSWISH>
__device__ __forceinline__ void store_bf16(u16* buf, const f32x4 (&acc)[2][4],
                                           int r0, int c0, int l16, int quad) {
#pragma unroll
  for (int ri = 0; ri < 2; ++ri)
#pragma unroll
    for (int reg = 0; reg < 4; ++reg) {
      int row = r0 + ri * 16 + quad * 4 + reg;
#pragma unroll
      for (int ci = 0; ci < 4; ++ci) {
        float v = acc[ri][ci][reg];
        if (DOSWISH) v = swishf(v);
        buf[(size_t)row * SP + c0 + ci * 16 + l16] = f2bf(v);
      }
    }
}

// ---------------- kernel: zero agg + cnt ----------------
__global__ void zero_kernel(float4* __restrict__ p, int n4) {
  int i = blockIdx.x * 256 + threadIdx.x;
  if (i < n4) p[i] = make_float4(0.f, 0.f, 0.f, 0.f);
}

// ---------------- kernel: weight bf16 swizzle  W[K][128] -> [K/8][128][8] ----------------
struct SwzSrc { const float* p[6]; };  // We2, Wu1, Wu2, Wp1, Wp2, Wo1

__global__ void swz_kernel(SwzSrc s, u16* __restrict__ wb) {
  int t = blockIdx.x * 256 + threadIdx.x;
  if (t >= G8_TOT * 128) return;
  int n = t & 127, g8 = t >> 7;
  int seg, base;
  if (g8 < G8_Wu1)      { seg = 0; base = G8_We2; }
  else if (g8 < G8_Wu2) { seg = 1; base = G8_Wu1; }
  else if (g8 < G8_Wp1) { seg = 2; base = G8_Wu2; }
  else if (g8 < G8_Wp2) { seg = 3; base = G8_Wp1; }
  else if (g8 < G8_Wo1) { seg = 4; base = G8_Wp2; }
  else                  { seg = 5; base = G8_Wo1; }
  const float* W = s.p[seg];
  int k8l = g8 - base;
  u16 v[8];
#pragma unroll
  for (int j = 0; j < 8; ++j) v[j] = f2bf(W[(size_t)(k8l * 8 + j) * 128 + n]);
  ((uint4*)wb)[g8 * 128 + n] = *(uint4*)v;
}

// ---------------- kernel: tau-conditioned scale/shift (3 sets) ----------------
__global__ void cond_kernel(const float* __restrict__ tau,
                            const float* __restrict__ Ce1, const float* __restrict__ ce1,
                            const float* __restrict__ Ce2, const float* __restrict__ ce2,
                            const float* __restrict__ Cu1, const float* __restrict__ cu1,
                            const float* __restrict__ Cu2, const float* __restrict__ cu2,
                            const float* __restrict__ Cp1, const float* __restrict__ cp1,
                            const float* __restrict__ Cp2, const float* __restrict__ cp2,
                            float* __restrict__ ss) {
  int set = blockIdx.x, b = blockIdx.y, j = threadIdx.x;
  const float *C1, *c1, *C2, *c2;
  if (set == 0)      { C1 = Ce1; c1 = ce1; C2 = Ce2; c2 = ce2; }
  else if (set == 1) { C1 = Cu1; c1 = cu1; C2 = Cu2; c2 = cu2; }
  else               { C1 = Cp1; c1 = cp1; C2 = Cp2; c2 = cp2; }
  float tf = tau[b];
  float a = c2[j];
  for (int k = 0; k < 16; ++k) {
    float h = swishf(tf * C1[k] + c1[k]);
    a = fmaf(h, C2[k * 256 + j], a);
  }
  ss[(size_t)set * cB * 256 + (size_t)b * 256 + j] = a;
}

// ---------------- fused MFMA edge pipeline (one batch), M=64 edges/block ----------------
// Two LDS data buffers only (bufE + reusable bufX) -> 37.9 KB -> 4 blocks/CU.
struct EWb { const float *We1, *be1, *be2, *bu1, *bu2; };

struct __align__(16) EdgeSmem {
  u16 bufE[64 * SP];   // h_embed -> e_emb (kept for final residual)
  u16 bufX[64 * SP];   // sf -> rf -> h2
  float ef4[256];
  float red[256];
  float musig[128];
  int sidx[64], ridx[64];
};

__global__ __launch_bounds__(256, 4) void edge_mfma(
    const float* __restrict__ rnode, const float* __restrict__ pnode,
    const float* __restrict__ efeat, const int* __restrict__ senders,
    const int* __restrict__ receivers, EWb w, const u16* __restrict__ wb,
    const float* __restrict__ ss, float* __restrict__ agg, float* __restrict__ cnt, int b) {
  __shared__ EdgeSmem sm;
  const int t = threadIdx.x, wv = t >> 6, lane = t & 63, l16 = lane & 15, quad = lane >> 4;
  const int r0 = (wv & 1) * 32, c0 = (wv >> 1) * 64;
  const int e0 = blockIdx.x * 64;

  if (t < 64) {
    sm.sidx[t] = min(max(senders[(size_t)b * cE + e0 + t], 0), cNR - 1);
    sm.ridx[t] = min(max(receivers[(size_t)b * cE + e0 + t], 0), cNP - 1);
  } else if (t >= 128) {
    ((float2*)sm.ef4)[t - 128] = ((const float2*)(efeat + ((size_t)b * cE + e0) * 4))[t - 128];
  }
  __syncthreads();  // b1

  // gather sender rows -> bufX (sf)
  for (int rr = 0; rr < 16; ++rr) {
    int row = wv * 16 + rr;
    float2 sv = *(const float2*)(rnode + ((size_t)b * cNR + sm.sidx[row]) * cF + lane * 2);
    *(unsigned*)(sm.bufX + (size_t)row * SP + lane * 2) = pack2(sv.x, sv.y);
  }

  // embed layer 1 (K=4, VALU) -> bufE
  {
    int col = t & 127, half = t >> 7;
    float w0 = w.We1[col], w1 = w.We1[128 + col], w2 = w.We1[256 + col], w3 = w.We1[384 + col];
    float bb = w.be1[col];
    for (int r = 0; r < 32; ++r) {
      int row = half * 32 + r;
      float a = fmaf(sm.ef4[row * 4 + 3], w3, fmaf(sm.ef4[row * 4 + 2], w2,
                fmaf(sm.ef4[row * 4 + 1], w1, fmaf(sm.ef4[row * 4 + 0], w0, bb))));
      sm.bufE[(size_t)row * SP + col] = f2bf(swishf(a));
    }
  }
  __syncthreads();  // b2: bufE(h_embed) + bufX(sf) visible

  f32x4 acc[2][4];

  // ---- embed L2 + cond-norm(set0) -> e_emb (bufE) ----
  init_acc(acc, w.be2, c0, l16);
  kloop128g(sm.bufE, wb + (size_t)G8_We2 * 1024, acc, r0, c0, l16, quad);
  cond_norm_mfma(acc, sm.red, sm.musig, ss + (size_t)b * 256, r0, c0, l16, quad, wv, t);
  store_bf16<false>(sm.bufE, acc, r0, c0, l16, quad);  // safe: all kloop reads pre-dated cn barriers
  __syncthreads();  // b3: e_emb visible

  // ---- update L1: K=384 over [e|sf|rf], accU in registers across bufX reload ----
  f32x4 accU[2][4];
  init_acc(accU, w.bu1, c0, l16);
  kloop128g(sm.bufE, wb + (size_t)G8_Wu1 * 1024, accU, r0, c0, l16, quad);
  kloop128g(sm.bufX, wb + (size_t)(G8_Wu1 + 16) * 1024, accU, r0, c0, l16, quad);
  __syncthreads();  // b4: all waves done reading bufX(sf)

  // gather receiver rows -> bufX (rf)
  for (int rr = 0; rr < 16; ++rr) {
    int row = wv * 16 + rr;
    float2 rv = *(const float2*)(pnode + ((size_t)b * cNP + sm.ridx[row]) * cF + lane * 2);
    *(unsigned*)(sm.bufX + (size_t)row * SP + lane * 2) = pack2(rv.x, rv.y);
  }
  __syncthreads();  // b5: bufX(rf) visible

  kloop128g(sm.bufX, wb + (size_t)(G8_Wu1 + 32) * 1024, accU, r0, c0, l16, quad);
  __syncthreads();  // b6: all waves done reading bufX(rf)
  store_bf16<true>(sm.bufX, accU, r0, c0, l16, quad);  // h2
  __syncthreads();  // b7: h2 visible

  // ---- update L2 + cond-norm(set1) ----
  init_acc(acc, w.bu2, c0, l16);
  kloop128g(sm.bufX, wb + (size_t)G8_Wu2 * 1024, acc, r0, c0, l16, quad);
  cond_norm_mfma(acc, sm.red, sm.musig, ss + (size_t)(cB + b) * 256, r0, c0, l16, quad, wv, t);

  // e = e_emb + u ; segment-sum atomics
#pragma unroll
  for (int ri = 0; ri < 2; ++ri)
#pragma unroll
    for (int reg = 0; reg < 4; ++reg) {
      int row = r0 + ri * 16 + quad * 4 + reg;
      size_t rbase = (size_t)sm.ridx[row] * cF;
#pragma unroll
      for (int ci = 0; ci < 4; ++ci) {
        int col = c0 + ci * 16 + l16;
        float v = acc[ri][ci][reg] + bf2f(sm.bufE[(size_t)row * SP + col]);
        atomicAdd(agg + rbase + col, v);
      }
    }
  if (t < 64) atomicAdd(cnt + sm.ridx[t], 1.0f);
}

// ---------------- fused MFMA pnode pipeline (one batch), M=64 nodes/block ----------------
struct PWb { const float *bp1, *bp2, *bo1, *Wo2, *bo2; };

struct __align__(16) PnodeSmem {
  u16 bufP[64 * SP];   // pf -> p_new
  u16 bufX[64 * SP];   // mean -> h1 -> h_out
  float red[256];
  float musig[128];
  float cinv[64];
};  // ~36.6 KB -> 4 blocks/CU

__global__ __launch_bounds__(256, 4) void pnode_mfma(
    const float* __restrict__ pnode, PWb w, const u16* __restrict__ wb,
    const float* __restrict__ ss, const float* __restrict__ agg,
    const float* __restrict__ cnt, float* __restrict__ out, int b) {
  __shared__ PnodeSmem sm;
  const int t = threadIdx.x, wv = t >> 6, lane = t & 63, l16 = lane & 15, quad = lane >> 4;
  const int r0 = (wv & 1) * 32, c0 = (wv >> 1) * 64;
  const int n0 = blockIdx.x * 64;

  if (t < 64) sm.cinv[t] = 1.0f / fmaxf(cnt[n0 + t], 1.0f);
  __syncthreads();  // b1

  for (int rr = 0; rr < 16; ++rr) {
    int row = wv * 16 + rr;
    float2 pv = *(const float2*)(pnode + ((size_t)b * cNP + n0 + row) * cF + lane * 2);
    float2 av = *(const float2*)(agg + (size_t)(n0 + row) * cF + lane * 2);
    float ci_ = sm.cinv[row];
    *(unsigned*)(sm.bufP + (size_t)row * SP + lane * 2) = pack2(pv.x, pv.y);
    *(unsigned*)(sm.bufX + (size_t)row * SP + lane * 2) = pack2(av.x * ci_, av.y * ci_);
  }
  __syncthreads();  // b2

  f32x4 acc[2][4];

  // ---- pnode L1: K=256 over [pf|mean] ----
  init_acc(acc, w.bp1, c0, l16);
  kloop128g(sm.bufP, wb + (size_t)G8_Wp1 * 1024, acc, r0, c0, l16, quad);
  kloop128g(sm.bufX, wb + (size_t)(G8_Wp1 + 16) * 1024, acc, r0, c0, l16, quad);
  __syncthreads();  // b3: all waves done reading bufX(mean)
  store_bf16<true>(sm.bufX, acc, r0, c0, l16, quad);  // h1
  __syncthreads();  // b4

  // ---- pnode L2 + cond-norm(set2) + residual -> bufP ----
  init_acc(acc, w.bp2, c0, l16);
  kloop128g(sm.bufX, wb + (size_t)G8_Wp2 * 1024, acc, r0, c0, l16, quad);
  cond_norm_mfma(acc, sm.red, sm.musig, ss + (size_t)(2 * cB + b) * 256, r0, c0, l16, quad, wv, t);
#pragma unroll
  for (int ri = 0; ri < 2; ++ri)
#pragma unroll
    for (int reg = 0; reg < 4; ++reg) {
      int row = r0 + ri * 16 + quad * 4 + reg;
#pragma unroll
      for (int ci = 0; ci < 4; ++ci)
        acc[ri][ci][reg] += bf2f(sm.bufP[(size_t)row * SP + c0 + ci * 16 + l16]);
    }
  __syncthreads();  // b5: all waves done residual-reading bufP
  store_bf16<false>(sm.bufP, acc, r0, c0, l16, quad);  // p_new
  __syncthreads();  // b6

  // ---- output L1: K=128 -> bufX ----
  init_acc(acc, w.bo1, c0, l16);
  kloop128g(sm.bufP, wb + (size_t)G8_Wo1 * 1024, acc, r0, c0, l16, quad);
  store_bf16<true>(sm.bufX, acc, r0, c0, l16, quad);  // bufX last read long before b6
  __syncthreads();  // b7

  // ---- output L2: K=128, N=4 (VALU, one output per thread) ----
  {
    int row = t >> 2, oc = t & 3;
    float a = w.bo2[oc];
    for (int k8 = 0; k8 < 16; ++k8) {
      s8v hv = *(const s8v*)(sm.bufX + (size_t)row * SP + k8 * 8);
#pragma unroll
      for (int j = 0; j < 8; ++j)
        a = fmaf(bf2f((u16)hv[j]), w.Wo2[(k8 * 8 + j) * 4 + oc], a);
    }
    out[((size_t)b * cNP + n0 + row) * 4 + oc] = a;
  }
}

// ---------------- launch ----------------
extern "C" void kernel_launch(void* const* d_in, const int* in_sizes, int n_in,
                              void* d_out, int out_size, void* d_ws, size_t ws_size,
                              hipStream_t stream) {
  const float* rnode = (const float*)d_in[0];
  const float* pnode = (const float*)d_in[1];
  const float* efeat = (const float*)d_in[2];
  const float* tau   = (const float*)d_in[3];
  const int* senders   = (const int*)d_in[40];
  const int* receivers = (const int*)d_in[41];
  float* ws = (float*)d_ws;
  u16* wb = (u16*)(ws + WS_WB);

  SwzSrc sw;
  sw.p[0] = (const float*)d_in[5];   // We2
  sw.p[1] = (const float*)d_in[12];  // Wu1
  sw.p[2] = (const float*)d_in[13];  // Wu2
  sw.p[3] = (const float*)d_in[20];  // Wp1
  sw.p[4] = (const float*)d_in[21];  // Wp2
  sw.p[5] = (const float*)d_in[36];  // Wo1
  swz_kernel<<<(G8_TOT * 128 + 255) / 256, 256, 0, stream>>>(sw, wb);

  cond_kernel<<<dim3(3, cB), 256, 0, stream>>>(
      tau,
      (const float*)d_in[8],  (const float*)d_in[10],
      (const float*)d_in[9],  (const float*)d_in[11],
      (const float*)d_in[16], (const float*)d_in[18],
      (const float*)d_in[17], (const float*)d_in[19],
      (const float*)d_in[24], (const float*)d_in[26],
      (const float*)d_in[25], (const float*)d_in[27],
      ws + WS_SS);

  EWb ew = { (const float*)d_in[4], (const float*)d_in[6], (const float*)d_in[7],
             (const float*)d_in[14], (const float*)d_in[15] };   // We1, be1, be2, bu1, bu2
  PWb pw = { (const float*)d_in[22], (const float*)d_in[23], (const float*)d_in[38],
             (const float*)d_in[37], (const float*)d_in[39] };   // bp1, bp2, bo1, Wo2, bo2

  const int n4 = (int)(WS_SS / 4);
  for (int b = 0; b < cB; ++b) {
    zero_kernel<<<(n4 + 255) / 256, 256, 0, stream>>>((float4*)ws, n4);
    edge_mfma<<<cE / 64, 256, 0, stream>>>(
        rnode, pnode, efeat, senders, receivers, ew, wb,
        ws + WS_SS, ws + WS_AGG, ws + WS_CNT, b);
    pnode_mfma<<<cNP / 64, 256, 0, stream>>>(
        pnode, pw, wb, ws + WS_SS, ws + WS_AGG, ws + WS_CNT,
        (float*)d_out, b);
  }
}

// Round 7
// 720.855 us; speedup vs baseline: 3.4354x; 1.0271x over previous
//
#include <hip/hip_runtime.h>

// ---------------- problem constants ----------------
constexpr int cB  = 2;
constexpr int cNR = 16384;
constexpr int cNP = 65536;
constexpr int cE  = 262144;
constexpr int cF  = 128;
constexpr int SP  = 136;   // bf16 row stride in LDS (2-way bank aliasing = free)

typedef unsigned short u16;
using f32x4 = __attribute__((ext_vector_type(4))) float;
using s8v   = __attribute__((ext_vector_type(8))) short;

// ws layout: agg is bf16 [B][NP][128] (32 MB), then cnt f32 [B][NP], then ss, then weights
constexpr size_t WS_CNT = ((size_t)cB * cNP * cF) / 2;   // float offset after bf16 agg
constexpr size_t WS_SS  = WS_CNT + (size_t)cB * cNP;     // 3 sets x [B,256]
constexpr size_t WS_WB  = WS_SS + 3 * cB * 256;          // swizzled bf16 weights

// swizzled-weight segment bases (units of k8 = 8 K-rows; one k8 = 1024 u16)
constexpr int G8_We2 = 0, G8_Wu1 = 16, G8_Wu2 = 64, G8_Wp1 = 80, G8_Wp2 = 112, G8_Wo1 = 128;
constexpr int G8_TOT = 144;

// ---------------- helpers ----------------
__device__ __forceinline__ float bf2f(u16 u) {
  union { unsigned int i; float f; } v; v.i = ((unsigned int)u) << 16; return v.f;
}
__device__ __forceinline__ u16 f2bf(float f) {
  union { float f; unsigned int i; } v; v.f = f;
  unsigned int x = v.i;
  return (u16)((x + 0x7fffu + ((x >> 16) & 1u)) >> 16);
}
__device__ __forceinline__ unsigned pack2(float a, float b) {
  return (unsigned)f2bf(a) | ((unsigned)f2bf(b) << 16);
}
__device__ __forceinline__ float swishf(float x) { return x / (1.0f + __expf(-x)); }

// packed bf16x2 atomic add (global_atomic_pk_add_bf16, gfx942+/gfx950)
__device__ __forceinline__ void atomic_pk_bf16(u16* addr, float lo, float hi) {
  unsigned data = pack2(lo, hi);
  unsigned long long a = (unsigned long long)addr;
  asm volatile("global_atomic_pk_add_bf16 %0, %1, off" :: "v"(a), "v"(data) : "memory");
}

// K=128 MFMA pass, M=64 tile: act = bf16 LDS [64][SP]; weights straight from
// global (L2-resident, swizzled [k8][128][8]) into registers.
__device__ __forceinline__ void kloop128g(const u16* act, const u16* __restrict__ wbg,
                                          f32x4 (&acc)[2][4], int r0, int c0, int l16, int quad) {
  s8v bf[4][4];
#pragma unroll
  for (int k0 = 0; k0 < 4; ++k0)
#pragma unroll
    for (int ci = 0; ci < 4; ++ci)
      bf[k0][ci] = *(const s8v*)(wbg + ((size_t)(k0 * 4 + quad) * 128 + c0 + ci * 16 + l16) * 8);
#pragma unroll
  for (int k0 = 0; k0 < 4; ++k0) {
    s8v af[2];
#pragma unroll
    for (int ri = 0; ri < 2; ++ri)
      af[ri] = *(const s8v*)(act + (size_t)(r0 + ri * 16 + l16) * SP + k0 * 32 + quad * 8);
#pragma unroll
    for (int ri = 0; ri < 2; ++ri)
#pragma unroll
      for (int ci = 0; ci < 4; ++ci)
        acc[ri][ci] = __builtin_amdgcn_mfma_f32_16x16x32_bf16(af[ri], bf[k0][ci], acc[ri][ci], 0, 0, 0);
  }
}

__device__ __forceinline__ void init_acc(f32x4 (&acc)[2][4], const float* __restrict__ bias,
                                         int c0, int l16) {
#pragma unroll
  for (int ci = 0; ci < 4; ++ci) {
    float bv = bias[c0 + ci * 16 + l16];
#pragma unroll
    for (int ri = 0; ri < 2; ++ri) acc[ri][ci] = (f32x4){bv, bv, bv, bv};
  }
}

// conditioned LayerNorm on MFMA C-layout, M=64 (wave covers 32 rows x 64 cols)
__device__ __forceinline__ void cond_norm_mfma(f32x4 (&acc)[2][4], float* red, float* musig,
                                               const float* __restrict__ ssp,
                                               int r0, int c0, int l16, int quad, int wv, int t) {
  __syncthreads();                 // all waves past their kloop LDS reads; red/musig reuse safe
  int wc = (wv >> 1) * 2;          // column-half slot
#pragma unroll
  for (int ri = 0; ri < 2; ++ri)
#pragma unroll
    for (int reg = 0; reg < 4; ++reg) {
      float v0 = acc[ri][0][reg], v1 = acc[ri][1][reg], v2 = acc[ri][2][reg], v3 = acc[ri][3][reg];
      float s = v0 + v1 + v2 + v3;
      float q = v0 * v0 + v1 * v1 + v2 * v2 + v3 * v3;
      s += __shfl_xor(s, 1); q += __shfl_xor(q, 1);
      s += __shfl_xor(s, 2); q += __shfl_xor(q, 2);
      s += __shfl_xor(s, 4); q += __shfl_xor(q, 4);
      s += __shfl_xor(s, 8); q += __shfl_xor(q, 8);
      if (l16 == 0) {
        int row = r0 + ri * 16 + quad * 4 + reg;
        red[row * 4 + wc]     = s;
        red[row * 4 + wc + 1] = q;
      }
    }
  __syncthreads();
  if (t < 64) {
    float sum = red[t * 4 + 0] + red[t * 4 + 2];
    float sq  = red[t * 4 + 1] + red[t * 4 + 3];
    float mu  = sum * (1.0f / 128.0f);
    float var = fmaxf(sq * (1.0f / 128.0f) - mu * mu, 0.0f);
    musig[t * 2]     = mu;
    musig[t * 2 + 1] = rsqrtf(var + 1e-6f);
  }
  __syncthreads();
  float scl[4], shf[4];
#pragma unroll
  for (int ci = 0; ci < 4; ++ci) {
    int col = c0 + ci * 16 + l16;
    scl[ci] = 1.0f + ssp[col];
    shf[ci] = ssp[128 + col];
  }
#pragma unroll
  for (int ri = 0; ri < 2; ++ri)
#pragma unroll
    for (int reg = 0; reg < 4; ++reg) {
      int row = r0 + ri * 16 + quad * 4 + reg;
      float mu = musig[row * 2], is = musig[row * 2 + 1];
#pragma unroll
      for (int ci = 0; ci < 4; ++ci)
        acc[ri][ci][reg] = (acc[ri][ci][reg] - mu) * is * scl[ci] + shf[ci];
    }
}

template <bool DOSWISH>
__device__ __forceinline__ void store_bf16(u16* buf, const f32x4 (&acc)[2][4],
                                           int r0, int c0, int l16, int quad) {
#pragma unroll
  for (int ri = 0; ri < 2; ++ri)
#pragma unroll
    for (int reg = 0; reg < 4; ++reg) {
      int row = r0 + ri * 16 + quad * 4 + reg;
#pragma unroll
      for (int ci = 0; ci < 4; ++ci) {
        float v = acc[ri][ci][reg];
        if (DOSWISH) v = swishf(v);
        buf[(size_t)row * SP + c0 + ci * 16 + l16] = f2bf(v);
      }
    }
}

// ---------------- kernel: zero agg (bf16) + cnt (f32) ----------------
__global__ void zero_kernel(float4* __restrict__ p, int n4) {
  int i = blockIdx.x * 256 + threadIdx.x;
  if (i < n4) p[i] = make_float4(0.f, 0.f, 0.f, 0.f);
}

// ---------------- kernel: weight bf16 swizzle  W[K][128] -> [K/8][128][8] ----------------
struct SwzSrc { const float* p[6]; };  // We2, Wu1, Wu2, Wp1, Wp2, Wo1

__global__ void swz_kernel(SwzSrc s, u16* __restrict__ wb) {
  int t = blockIdx.x * 256 + threadIdx.x;
  if (t >= G8_TOT * 128) return;
  int n = t & 127, g8 = t >> 7;
  int seg, base;
  if (g8 < G8_Wu1)      { seg = 0; base = G8_We2; }
  else if (g8 < G8_Wu2) { seg = 1; base = G8_Wu1; }
  else if (g8 < G8_Wp1) { seg = 2; base = G8_Wu2; }
  else if (g8 < G8_Wp2) { seg = 3; base = G8_Wp1; }
  else if (g8 < G8_Wo1) { seg = 4; base = G8_Wp2; }
  else                  { seg = 5; base = G8_Wo1; }
  const float* W = s.p[seg];
  int k8l = g8 - base;
  u16 v[8];
#pragma unroll
  for (int j = 0; j < 8; ++j) v[j] = f2bf(W[(size_t)(k8l * 8 + j) * 128 + n]);
  ((uint4*)wb)[g8 * 128 + n] = *(uint4*)v;
}

// ---------------- kernel: tau-conditioned scale/shift (3 sets) ----------------
__global__ void cond_kernel(const float* __restrict__ tau,
                            const float* __restrict__ Ce1, const float* __restrict__ ce1,
                            const float* __restrict__ Ce2, const float* __restrict__ ce2,
                            const float* __restrict__ Cu1, const float* __restrict__ cu1,
                            const float* __restrict__ Cu2, const float* __restrict__ cu2,
                            const float* __restrict__ Cp1, const float* __restrict__ cp1,
                            const float* __restrict__ Cp2, const float* __restrict__ cp2,
                            float* __restrict__ ss) {
  int set = blockIdx.x, b = blockIdx.y, j = threadIdx.x;
  const float *C1, *c1, *C2, *c2;
  if (set == 0)      { C1 = Ce1; c1 = ce1; C2 = Ce2; c2 = ce2; }
  else if (set == 1) { C1 = Cu1; c1 = cu1; C2 = Cu2; c2 = cu2; }
  else               { C1 = Cp1; c1 = cp1; C2 = Cp2; c2 = cp2; }
  float tf = tau[b];
  float a = c2[j];
  for (int k = 0; k < 16; ++k) {
    float h = swishf(tf * C1[k] + c1[k]);
    a = fmaf(h, C2[k * 256 + j], a);
  }
  ss[(size_t)set * cB * 256 + (size_t)b * 256 + j] = a;
}

// ---------------- fused MFMA edge pipeline (both batches), M=64 edges/block ----------------
struct EWb { const float *We1, *be1, *be2, *bu1, *bu2; };

struct __align__(16) EdgeSmem {
  u16 bufE[64 * SP];   // h_embed -> e_emb (kept for final residual)
  u16 bufX[64 * SP];   // sf -> rf -> h2
  float ef4[256];
  float red[256];
  float musig[128];
  int sidx[64], ridx[64];
};  // ~37.9 KB -> 4 blocks/CU

__global__ __launch_bounds__(256, 4) void edge_mfma(
    const float* __restrict__ rnode, const float* __restrict__ pnode,
    const float* __restrict__ efeat, const int* __restrict__ senders,
    const int* __restrict__ receivers, EWb w, const u16* __restrict__ wb,
    const float* __restrict__ ss, u16* __restrict__ aggb, float* __restrict__ cnt) {
  __shared__ EdgeSmem sm;
  const int t = threadIdx.x, wv = t >> 6, lane = t & 63, l16 = lane & 15, quad = lane >> 4;
  const int r0 = (wv & 1) * 32, c0 = (wv >> 1) * 64;
  const int b  = blockIdx.y;
  const int e0 = blockIdx.x * 64;

  if (t < 64) {
    sm.sidx[t] = min(max(senders[(size_t)b * cE + e0 + t], 0), cNR - 1);
    sm.ridx[t] = min(max(receivers[(size_t)b * cE + e0 + t], 0), cNP - 1);
  } else if (t >= 128) {
    ((float2*)sm.ef4)[t - 128] = ((const float2*)(efeat + ((size_t)b * cE + e0) * 4))[t - 128];
  }
  __syncthreads();  // b1

  // gather sender rows -> bufX (sf)
  for (int rr = 0; rr < 16; ++rr) {
    int row = wv * 16 + rr;
    float2 sv = *(const float2*)(rnode + ((size_t)b * cNR + sm.sidx[row]) * cF + lane * 2);
    *(unsigned*)(sm.bufX + (size_t)row * SP + lane * 2) = pack2(sv.x, sv.y);
  }

  // embed layer 1 (K=4, VALU) -> bufE
  {
    int col = t & 127, half = t >> 7;
    float w0 = w.We1[col], w1 = w.We1[128 + col], w2 = w.We1[256 + col], w3 = w.We1[384 + col];
    float bb = w.be1[col];
    for (int r = 0; r < 32; ++r) {
      int row = half * 32 + r;
      float a = fmaf(sm.ef4[row * 4 + 3], w3, fmaf(sm.ef4[row * 4 + 2], w2,
                fmaf(sm.ef4[row * 4 + 1], w1, fmaf(sm.ef4[row * 4 + 0], w0, bb))));
      sm.bufE[(size_t)row * SP + col] = f2bf(swishf(a));
    }
  }
  __syncthreads();  // b2: bufE(h_embed) + bufX(sf) visible

  f32x4 acc[2][4];

  // ---- embed L2 + cond-norm(set0) -> e_emb (bufE) ----
  init_acc(acc, w.be2, c0, l16);
  kloop128g(sm.bufE, wb + (size_t)G8_We2 * 1024, acc, r0, c0, l16, quad);
  cond_norm_mfma(acc, sm.red, sm.musig, ss + (size_t)b * 256, r0, c0, l16, quad, wv, t);
  store_bf16<false>(sm.bufE, acc, r0, c0, l16, quad);
  __syncthreads();  // b3: e_emb visible

  // ---- update L1: K=384 over [e|sf|rf], accU in registers across bufX reload ----
  f32x4 accU[2][4];
  init_acc(accU, w.bu1, c0, l16);
  kloop128g(sm.bufE, wb + (size_t)G8_Wu1 * 1024, accU, r0, c0, l16, quad);
  kloop128g(sm.bufX, wb + (size_t)(G8_Wu1 + 16) * 1024, accU, r0, c0, l16, quad);
  __syncthreads();  // b4: all waves done reading bufX(sf)

  // gather receiver rows -> bufX (rf)
  for (int rr = 0; rr < 16; ++rr) {
    int row = wv * 16 + rr;
    float2 rv = *(const float2*)(pnode + ((size_t)b * cNP + sm.ridx[row]) * cF + lane * 2);
    *(unsigned*)(sm.bufX + (size_t)row * SP + lane * 2) = pack2(rv.x, rv.y);
  }
  __syncthreads();  // b5: bufX(rf) visible

  kloop128g(sm.bufX, wb + (size_t)(G8_Wu1 + 32) * 1024, accU, r0, c0, l16, quad);
  __syncthreads();  // b6: all waves done reading bufX(rf)
  store_bf16<true>(sm.bufX, accU, r0, c0, l16, quad);  // h2
  __syncthreads();  // b7: h2 visible

  // ---- update L2 + cond-norm(set1) ----
  init_acc(acc, w.bu2, c0, l16);
  kloop128g(sm.bufX, wb + (size_t)G8_Wu2 * 1024, acc, r0, c0, l16, quad);
  cond_norm_mfma(acc, sm.red, sm.musig, ss + (size_t)(cB + b) * 256, r0, c0, l16, quad, wv, t);

  // e = e_emb + u ; packed-bf16 segment-sum atomics (adjacent lanes pair up)
#pragma unroll
  for (int ri = 0; ri < 2; ++ri)
#pragma unroll
    for (int reg = 0; reg < 4; ++reg) {
      int row = r0 + ri * 16 + quad * 4 + reg;
      size_t rbase = ((size_t)b * cNP + sm.ridx[row]) * cF;
#pragma unroll
      for (int ci = 0; ci < 4; ++ci) {
        int col = c0 + ci * 16 + l16;
        float v = acc[ri][ci][reg] + bf2f(sm.bufE[(size_t)row * SP + col]);
        float vo = __shfl_xor(v, 1);
        if ((l16 & 1) == (ci >> 1)) {   // even lanes: ci 0,1 ; odd lanes: ci 2,3
          int colb = col & ~1;
          float lo = (l16 & 1) ? vo : v;
          float hi = (l16 & 1) ? v : vo;
          atomic_pk_bf16(aggb + rbase + colb, lo, hi);
        }
      }
    }
  if (t < 64) atomicAdd(cnt + (size_t)b * cNP + sm.ridx[t], 1.0f);
}

// ---------------- fused MFMA pnode pipeline (both batches), M=64 nodes/block ----------------
struct PWb { const float *bp1, *bp2, *bo1, *Wo2, *bo2; };

struct __align__(16) PnodeSmem {
  u16 bufP[64 * SP];   // pf -> p_new
  u16 bufX[64 * SP];   // mean -> h1 -> h_out
  float red[256];
  float musig[128];
  float cinv[64];
};  // ~36.6 KB -> 4 blocks/CU

__global__ __launch_bounds__(256, 4) void pnode_mfma(
    const float* __restrict__ pnode, PWb w, const u16* __restrict__ wb,
    const float* __restrict__ ss, const u16* __restrict__ aggb,
    const float* __restrict__ cnt, float* __restrict__ out) {
  __shared__ PnodeSmem sm;
  const int t = threadIdx.x, wv = t >> 6, lane = t & 63, l16 = lane & 15, quad = lane >> 4;
  const int r0 = (wv & 1) * 32, c0 = (wv >> 1) * 64;
  const int b  = blockIdx.y;
  const int n0 = blockIdx.x * 64;

  if (t < 64) sm.cinv[t] = 1.0f / fmaxf(cnt[(size_t)b * cNP + n0 + t], 1.0f);
  __syncthreads();  // b1

  for (int rr = 0; rr < 16; ++rr) {
    int row = wv * 16 + rr;
    float2 pv = *(const float2*)(pnode + ((size_t)b * cNP + n0 + row) * cF + lane * 2);
    unsigned avu = *(const unsigned*)(aggb + (((size_t)b * cNP + n0 + row) * cF + lane * 2));
    float ci_ = sm.cinv[row];
    float a0 = bf2f((u16)(avu & 0xffffu)) * ci_;
    float a1 = bf2f((u16)(avu >> 16)) * ci_;
    *(unsigned*)(sm.bufP + (size_t)row * SP + lane * 2) = pack2(pv.x, pv.y);
    *(unsigned*)(sm.bufX + (size_t)row * SP + lane * 2) = pack2(a0, a1);
  }
  __syncthreads();  // b2

  f32x4 acc[2][4];

  // ---- pnode L1: K=256 over [pf|mean] ----
  init_acc(acc, w.bp1, c0, l16);
  kloop128g(sm.bufP, wb + (size_t)G8_Wp1 * 1024, acc, r0, c0, l16, quad);
  kloop128g(sm.bufX, wb + (size_t)(G8_Wp1 + 16) * 1024, acc, r0, c0, l16, quad);
  __syncthreads();  // b3: all waves done reading bufX(mean)
  store_bf16<true>(sm.bufX, acc, r0, c0, l16, quad);  // h1
  __syncthreads();  // b4

  // ---- pnode L2 + cond-norm(set2) + residual -> bufP ----
  init_acc(acc, w.bp2, c0, l16);
  kloop128g(sm.bufX, wb + (size_t)G8_Wp2 * 1024, acc, r0, c0, l16, quad);
  cond_norm_mfma(acc, sm.red, sm.musig, ss + (size_t)(2 * cB + b) * 256, r0, c0, l16, quad, wv, t);
#pragma unroll
  for (int ri = 0; ri < 2; ++ri)
#pragma unroll
    for (int reg = 0; reg < 4; ++reg) {
      int row = r0 + ri * 16 + quad * 4 + reg;
#pragma unroll
      for (int ci = 0; ci < 4; ++ci)
        acc[ri][ci][reg] += bf2f(sm.bufP[(size_t)row * SP + c0 + ci * 16 + l16]);
    }
  __syncthreads();  // b5: all waves done residual-reading bufP
  store_bf16<false>(sm.bufP, acc, r0, c0, l16, quad);  // p_new
  __syncthreads();  // b6

  // ---- output L1: K=128 -> bufX ----
  init_acc(acc, w.bo1, c0, l16);
  kloop128g(sm.bufP, wb + (size_t)G8_Wo1 * 1024, acc, r0, c0, l16, quad);
  store_bf16<true>(sm.bufX, acc, r0, c0, l16, quad);
  __syncthreads();  // b7

  // ---- output L2: K=128, N=4 (VALU, one output per thread) ----
  {
    int row = t >> 2, oc = t & 3;
    float a = w.bo2[oc];
    for (int k8 = 0; k8 < 16; ++k8) {
      s8v hv = *(const s8v*)(sm.bufX + (size_t)row * SP + k8 * 8);
#pragma unroll
      for (int j = 0; j < 8; ++j)
        a = fmaf(bf2f((u16)hv[j]), w.Wo2[(k8 * 8 + j) * 4 + oc], a);
    }
    out[((size_t)b * cNP + n0 + row) * 4 + oc] = a;
  }
}

// ---------------- launch ----------------
extern "C" void kernel_launch(void* const* d_in, const int* in_sizes, int n_in,
                              void* d_out, int out_size, void* d_ws, size_t ws_size,
                              hipStream_t stream) {
  const float* rnode = (const float*)d_in[0];
  const float* pnode = (const float*)d_in[1];
  const float* efeat = (const float*)d_in[2];
  const float* tau   = (const float*)d_in[3];
  const int* senders   = (const int*)d_in[40];
  const int* receivers = (const int*)d_in[41];
  float* ws = (float*)d_ws;
  u16* aggb = (u16*)d_ws;                 // bf16 [B][NP][128]
  u16* wb   = (u16*)(ws + WS_WB);

  SwzSrc sw;
  sw.p[0] = (const float*)d_in[5];   // We2
  sw.p[1] = (const float*)d_in[12];  // Wu1
  sw.p[2] = (const float*)d_in[13];  // Wu2
  sw.p[3] = (const float*)d_in[20];  // Wp1
  sw.p[4] = (const float*)d_in[21];  // Wp2
  sw.p[5] = (const float*)d_in[36];  // Wo1
  swz_kernel<<<(G8_TOT * 128 + 255) / 256, 256, 0, stream>>>(sw, wb);

  cond_kernel<<<dim3(3, cB), 256, 0, stream>>>(
      tau,
      (const float*)d_in[8],  (const float*)d_in[10],
      (const float*)d_in[9],  (const float*)d_in[11],
      (const float*)d_in[16], (const float*)d_in[18],
      (const float*)d_in[17], (const float*)d_in[19],
      (const float*)d_in[24], (const float*)d_in[26],
      (const float*)d_in[25], (const float*)d_in[27],
      ws + WS_SS);

  EWb ew = { (const float*)d_in[4], (const float*)d_in[6], (const float*)d_in[7],
             (const float*)d_in[14], (const float*)d_in[15] };   // We1, be1, be2, bu1, bu2
  PWb pw = { (const float*)d_in[22], (const float*)d_in[23], (const float*)d_in[38],
             (const float*)d_in[37], (const float*)d_in[39] };   // bp1, bp2, bo1, Wo2, bo2

  // zero agg (bf16) + cnt (f32): WS_SS floats total, exactly divisible by 4
  const int n4 = (int)(WS_SS / 4);
  zero_kernel<<<(n4 + 255) / 256, 256, 0, stream>>>((float4*)ws, n4);

  edge_mfma<<<dim3(cE / 64, cB), 256, 0, stream>>>(
      rnode, pnode, efeat, senders, receivers, ew, wb,
      ws + WS_SS, aggb, ws + WS_CNT);

  pnode_mfma<<<dim3(cNP / 64, cB), 256, 0, stream>>>(
      pnode, pw, wb, ws + WS_SS, aggb, ws + WS_CNT,
      (float*)d_out);
}

// Round 8
// 601.292 us; speedup vs baseline: 4.1185x; 1.1988x over previous
//
#include <hip/hip_runtime.h>

// ---------------- problem constants ----------------
constexpr int cB  = 2;
constexpr int cNR = 16384;
constexpr int cNP = 65536;
constexpr int cE  = 262144;
constexpr int cF  = 128;
constexpr int SP  = 136;   // bf16 row stride in LDS (2-way bank aliasing = free)

typedef unsigned short u16;
using f32x4 = __attribute__((ext_vector_type(4))) float;
using s8v   = __attribute__((ext_vector_type(8))) short;

// ws layout: agg bf16 [B][NP][128] (32 MB), cnt f32 [B][NP], ss, swizzled weights
constexpr size_t WS_CNT = ((size_t)cB * cNP * cF) / 2;
constexpr size_t WS_SS  = WS_CNT + (size_t)cB * cNP;
constexpr size_t WS_WB  = WS_SS + 3 * cB * 256;

// swizzled-weight segment bases (units of k8 = 8 K-rows; one k8 = 1024 u16)
constexpr int G8_We2 = 0, G8_Wu1 = 16, G8_Wu2 = 64, G8_Wp1 = 80, G8_Wp2 = 112, G8_Wo1 = 128;
constexpr int G8_TOT = 144;

// ---------------- helpers ----------------
__device__ __forceinline__ float bf2f(u16 u) {
  union { unsigned int i; float f; } v; v.i = ((unsigned int)u) << 16; return v.f;
}
__device__ __forceinline__ u16 f2bf(float f) {        // RNE (weights only)
  union { float f; unsigned int i; } v; v.f = f;
  unsigned int x = v.i;
  return (u16)((x + 0x7fffu + ((x >> 16) & 1u)) >> 16);
}
// fast round-half-up bf16 (intermediates; 2 VALU ops)
__device__ __forceinline__ u16 f2bf_fast(float f) {
  return (u16)((__float_as_uint(f) + 0x8000u) >> 16);
}
// packed pair via v_perm_b32 (3 VALU ops total)
__device__ __forceinline__ unsigned pack2(float a, float b) {
  return __builtin_amdgcn_perm(__float_as_uint(b) + 0x8000u,
                               __float_as_uint(a) + 0x8000u, 0x07060302u);
}
__device__ __forceinline__ float swishf(float x) { return x / (1.0f + __expf(-x)); }

// packed bf16x2 atomic add (global_atomic_pk_add_bf16, gfx950)
__device__ __forceinline__ void atomic_pk_bf16(u16* addr, float lo, float hi) {
  unsigned data = pack2(lo, hi);
  unsigned long long a = (unsigned long long)addr;
  asm volatile("global_atomic_pk_add_bf16 %0, %1, off" :: "v"(a), "v"(data) : "memory");
}

// ---- column-strip MFMA pass: wave covers rows 0..63 x 32-col strip (cw) ----
// act: bf16 LDS [64][SP]; weights from global swizzled [k8][128][8].
__device__ __forceinline__ void kloop128s(const u16* act, const u16* __restrict__ wbg,
                                          f32x4 (&acc)[4][2], int cw, int l16, int quad) {
  s8v bf[4][2];
#pragma unroll
  for (int k0 = 0; k0 < 4; ++k0)
#pragma unroll
    for (int ci = 0; ci < 2; ++ci)
      bf[k0][ci] = *(const s8v*)(wbg + ((size_t)(k0 * 4 + quad) * 128 + cw + ci * 16 + l16) * 8);
#pragma unroll
  for (int k0 = 0; k0 < 4; ++k0) {
    s8v af[4];
#pragma unroll
    for (int ri = 0; ri < 4; ++ri)
      af[ri] = *(const s8v*)(act + (size_t)(ri * 16 + l16) * SP + k0 * 32 + quad * 8);
#pragma unroll
    for (int ri = 0; ri < 4; ++ri)
#pragma unroll
      for (int ci = 0; ci < 2; ++ci)
        acc[ri][ci] = __builtin_amdgcn_mfma_f32_16x16x32_bf16(af[ri], bf[k0][ci], acc[ri][ci], 0, 0, 0);
  }
}

__device__ __forceinline__ void init_acc_s(f32x4 (&acc)[4][2], const float* __restrict__ bias,
                                           int cw, int l16) {
#pragma unroll
  for (int ci = 0; ci < 2; ++ci) {
    float bv = bias[cw + ci * 16 + l16];
#pragma unroll
    for (int ri = 0; ri < 4; ++ri) acc[ri][ci] = (f32x4){bv, bv, bv, bv};
  }
}

// conditioned LayerNorm on strip C-layout: row = ri*16+quad*4+reg, wave owns 32 cols
__device__ __forceinline__ void cond_norm_s(f32x4 (&acc)[4][2], float* red, float* musig,
                                            const float* __restrict__ ssp,
                                            int cw, int l16, int quad, int wv, int t) {
  __syncthreads();                 // prior LDS reads done; red/musig reuse safe
#pragma unroll
  for (int ri = 0; ri < 4; ++ri)
#pragma unroll
    for (int reg = 0; reg < 4; ++reg) {
      float v0 = acc[ri][0][reg], v1 = acc[ri][1][reg];
      float s = v0 + v1;
      float q = v0 * v0 + v1 * v1;
      s += __shfl_xor(s, 1); q += __shfl_xor(q, 1);
      s += __shfl_xor(s, 2); q += __shfl_xor(q, 2);
      s += __shfl_xor(s, 4); q += __shfl_xor(q, 4);
      s += __shfl_xor(s, 8); q += __shfl_xor(q, 8);
      if (l16 == 0) {
        int row = ri * 16 + quad * 4 + reg;
        red[row * 8 + wv * 2]     = s;
        red[row * 8 + wv * 2 + 1] = q;
      }
    }
  __syncthreads();
  if (t < 64) {
    float sum = red[t * 8 + 0] + red[t * 8 + 2] + red[t * 8 + 4] + red[t * 8 + 6];
    float sq  = red[t * 8 + 1] + red[t * 8 + 3] + red[t * 8 + 5] + red[t * 8 + 7];
    float mu  = sum * (1.0f / 128.0f);
    float var = fmaxf(sq * (1.0f / 128.0f) - mu * mu, 0.0f);
    musig[t * 2]     = mu;
    musig[t * 2 + 1] = rsqrtf(var + 1e-6f);
  }
  __syncthreads();
  float scl[2], shf[2];
#pragma unroll
  for (int ci = 0; ci < 2; ++ci) {
    int col = cw + ci * 16 + l16;
    scl[ci] = 1.0f + ssp[col];
    shf[ci] = ssp[128 + col];
  }
#pragma unroll
  for (int ri = 0; ri < 4; ++ri)
#pragma unroll
    for (int reg = 0; reg < 4; ++reg) {
      int row = ri * 16 + quad * 4 + reg;
      float mu = musig[row * 2], is = musig[row * 2 + 1];
#pragma unroll
      for (int ci = 0; ci < 2; ++ci)
        acc[ri][ci][reg] = (acc[ri][ci][reg] - mu) * is * scl[ci] + shf[ci];
    }
}

template <bool DOSWISH>
__device__ __forceinline__ void store_s(u16* buf, const f32x4 (&acc)[4][2],
                                        int cw, int l16, int quad) {
#pragma unroll
  for (int ri = 0; ri < 4; ++ri)
#pragma unroll
    for (int reg = 0; reg < 4; ++reg) {
      int row = ri * 16 + quad * 4 + reg;
#pragma unroll
      for (int ci = 0; ci < 2; ++ci) {
        float v = acc[ri][ci][reg];
        if (DOSWISH) v = swishf(v);
        buf[(size_t)row * SP + cw + ci * 16 + l16] = f2bf_fast(v);
      }
    }
}

// ---------------- kernel: zero agg (bf16) + cnt (f32) ----------------
__global__ void zero_kernel(float4* __restrict__ p, int n4) {
  int i = blockIdx.x * 256 + threadIdx.x;
  if (i < n4) p[i] = make_float4(0.f, 0.f, 0.f, 0.f);
}

// ---------------- kernel: weight bf16 swizzle  W[K][128] -> [K/8][128][8] ----------------
struct SwzSrc { const float* p[6]; };  // We2, Wu1, Wu2, Wp1, Wp2, Wo1

__global__ void swz_kernel(SwzSrc s, u16* __restrict__ wb) {
  int t = blockIdx.x * 256 + threadIdx.x;
  if (t >= G8_TOT * 128) return;
  int n = t & 127, g8 = t >> 7;
  int seg, base;
  if (g8 < G8_Wu1)      { seg = 0; base = G8_We2; }
  else if (g8 < G8_Wu2) { seg = 1; base = G8_Wu1; }
  else if (g8 < G8_Wp1) { seg = 2; base = G8_Wu2; }
  else if (g8 < G8_Wp2) { seg = 3; base = G8_Wp1; }
  else if (g8 < G8_Wo1) { seg = 4; base = G8_Wp2; }
  else                  { seg = 5; base = G8_Wo1; }
  const float* W = s.p[seg];
  int k8l = g8 - base;
  u16 v[8];
#pragma unroll
  for (int j = 0; j < 8; ++j) v[j] = f2bf(W[(size_t)(k8l * 8 + j) * 128 + n]);
  ((uint4*)wb)[g8 * 128 + n] = *(uint4*)v;
}

// ---------------- kernel: tau-conditioned scale/shift (3 sets) ----------------
__global__ void cond_kernel(const float* __restrict__ tau,
                            const float* __restrict__ Ce1, const float* __restrict__ ce1,
                            const float* __restrict__ Ce2, const float* __restrict__ ce2,
                            const float* __restrict__ Cu1, const float* __restrict__ cu1,
                            const float* __restrict__ Cu2, const float* __restrict__ cu2,
                            const float* __restrict__ Cp1, const float* __restrict__ cp1,
                            const float* __restrict__ Cp2, const float* __restrict__ cp2,
                            float* __restrict__ ss) {
  int set = blockIdx.x, b = blockIdx.y, j = threadIdx.x;
  const float *C1, *c1, *C2, *c2;
  if (set == 0)      { C1 = Ce1; c1 = ce1; C2 = Ce2; c2 = ce2; }
  else if (set == 1) { C1 = Cu1; c1 = cu1; C2 = Cu2; c2 = cu2; }
  else               { C1 = Cp1; c1 = cp1; C2 = Cp2; c2 = cp2; }
  float tf = tau[b];
  float a = c2[j];
  for (int k = 0; k < 16; ++k) {
    float h = swishf(tf * C1[k] + c1[k]);
    a = fmaf(h, C2[k * 256 + j], a);
  }
  ss[(size_t)set * cB * 256 + (size_t)b * 256 + j] = a;
}

// ---------------- fused MFMA edge pipeline (both batches), M=64 edges/block ----------------
struct EWb { const float *We1, *be1, *be2, *bu1, *bu2; };

struct __align__(16) EdgeSmem {
  u16 bufE[64 * SP];   // h_embed -> e_emb (kept for final residual)
  u16 bufX[64 * SP];   // sf -> rf -> h2
  float ef4[256];
  float red[512];
  float musig[128];
  int sidx[64], ridx[64];
};  // ~38.9 KB -> 4 blocks/CU

__global__ __launch_bounds__(256, 4) void edge_mfma(
    const float* __restrict__ rnode, const float* __restrict__ pnode,
    const float* __restrict__ efeat, const int* __restrict__ senders,
    const int* __restrict__ receivers, EWb w, const u16* __restrict__ wb,
    const float* __restrict__ ss, u16* __restrict__ aggb, float* __restrict__ cnt) {
  __shared__ EdgeSmem sm;
  const int t = threadIdx.x, wv = t >> 6, lane = t & 63, l16 = lane & 15, quad = lane >> 4;
  const int cw = wv * 32;          // column strip base
  const int b  = blockIdx.y;
  const int e0 = blockIdx.x * 64;

  if (t < 64) {
    sm.sidx[t] = min(max(senders[(size_t)b * cE + e0 + t], 0), cNR - 1);
    sm.ridx[t] = min(max(receivers[(size_t)b * cE + e0 + t], 0), cNP - 1);
  } else if (t >= 128) {
    ((float2*)sm.ef4)[t - 128] = ((const float2*)(efeat + ((size_t)b * cE + e0) * 4))[t - 128];
  }
  __syncthreads();  // b1

  // gather sf -> bufX now; rf -> registers (consumed after b4, latency hidden)
  unsigned rfp[16];
#pragma unroll
  for (int rr = 0; rr < 16; ++rr) {
    int row = wv * 16 + rr;
    float2 sv = *(const float2*)(rnode + ((size_t)b * cNR + sm.sidx[row]) * cF + lane * 2);
    float2 rv = *(const float2*)(pnode + ((size_t)b * cNP + sm.ridx[row]) * cF + lane * 2);
    *(unsigned*)(sm.bufX + (size_t)row * SP + lane * 2) = pack2(sv.x, sv.y);
    rfp[rr] = pack2(rv.x, rv.y);
  }

  // embed layer 1 (K=4, VALU) -> bufE
  {
    int col = t & 127, half = t >> 7;
    float w0 = w.We1[col], w1 = w.We1[128 + col], w2 = w.We1[256 + col], w3 = w.We1[384 + col];
    float bb = w.be1[col];
    for (int r = 0; r < 32; ++r) {
      int row = half * 32 + r;
      float a = fmaf(sm.ef4[row * 4 + 3], w3, fmaf(sm.ef4[row * 4 + 2], w2,
                fmaf(sm.ef4[row * 4 + 1], w1, fmaf(sm.ef4[row * 4 + 0], w0, bb))));
      sm.bufE[(size_t)row * SP + col] = f2bf_fast(swishf(a));
    }
  }
  __syncthreads();  // b2: bufE(h_embed) + bufX(sf) visible

  f32x4 acc[4][2];

  // ---- embed L2 + cond-norm(set0) -> e_emb (bufE) ----
  init_acc_s(acc, w.be2, cw, l16);
  kloop128s(sm.bufE, wb + (size_t)G8_We2 * 1024, acc, cw, l16, quad);
  cond_norm_s(acc, sm.red, sm.musig, ss + (size_t)b * 256, cw, l16, quad, wv, t);
  store_s<false>(sm.bufE, acc, cw, l16, quad);
  __syncthreads();  // b3: e_emb visible

  // ---- update L1: K=384 over [e|sf|rf] ----
  f32x4 accU[4][2];
  init_acc_s(accU, w.bu1, cw, l16);
  kloop128s(sm.bufE, wb + (size_t)G8_Wu1 * 1024, accU, cw, l16, quad);
  kloop128s(sm.bufX, wb + (size_t)(G8_Wu1 + 16) * 1024, accU, cw, l16, quad);
  __syncthreads();  // b4: all waves done reading bufX(sf)

  // spill prefetched rf regs -> bufX
#pragma unroll
  for (int rr = 0; rr < 16; ++rr)
    *(unsigned*)(sm.bufX + (size_t)(wv * 16 + rr) * SP + lane * 2) = rfp[rr];
  __syncthreads();  // b5: bufX(rf) visible

  kloop128s(sm.bufX, wb + (size_t)(G8_Wu1 + 32) * 1024, accU, cw, l16, quad);
  __syncthreads();  // b6: all waves done reading bufX(rf)
  store_s<true>(sm.bufX, accU, cw, l16, quad);  // h2
  __syncthreads();  // b7: h2 visible

  // ---- update L2 + cond-norm(set1) ----
  init_acc_s(acc, w.bu2, cw, l16);
  kloop128s(sm.bufX, wb + (size_t)G8_Wu2 * 1024, acc, cw, l16, quad);
  cond_norm_s(acc, sm.red, sm.musig, ss + (size_t)(cB + b) * 256, cw, l16, quad, wv, t);

  // e = e_emb + u ; packed-bf16 segment-sum atomics (even lane pairs with odd)
#pragma unroll
  for (int ri = 0; ri < 4; ++ri)
#pragma unroll
    for (int reg = 0; reg < 4; ++reg) {
      int row = ri * 16 + quad * 4 + reg;
      size_t rbase = ((size_t)b * cNP + sm.ridx[row]) * cF;
#pragma unroll
      for (int ci = 0; ci < 2; ++ci) {
        int col = cw + ci * 16 + l16;
        float v = acc[ri][ci][reg] + bf2f(sm.bufE[(size_t)row * SP + col]);
        float vo = __shfl_xor(v, 1);
        if (!(lane & 1)) atomic_pk_bf16(aggb + rbase + col, v, vo);
      }
    }
  if (t < 64) atomicAdd(cnt + (size_t)b * cNP + sm.ridx[t], 1.0f);
}

// ---------------- fused MFMA pnode pipeline (both batches), M=64 nodes/block ----------------
struct PWb { const float *bp1, *bp2, *bo1, *Wo2, *bo2; };

struct __align__(16) PnodeSmem {
  u16 bufP[64 * SP];   // pf -> p_new
  u16 bufX[64 * SP];   // mean -> h1 -> h_out
  float red[512];
  float musig[128];
  float cinv[64];
};  // ~37.6 KB -> 4 blocks/CU

__global__ __launch_bounds__(256, 4) void pnode_mfma(
    const float* __restrict__ pnode, PWb w, const u16* __restrict__ wb,
    const float* __restrict__ ss, const u16* __restrict__ aggb,
    const float* __restrict__ cnt, float* __restrict__ out) {
  __shared__ PnodeSmem sm;
  const int t = threadIdx.x, wv = t >> 6, lane = t & 63, l16 = lane & 15, quad = lane >> 4;
  const int cw = wv * 32;
  const int b  = blockIdx.y;
  const int n0 = blockIdx.x * 64;

  if (t < 64) sm.cinv[t] = 1.0f / fmaxf(cnt[(size_t)b * cNP + n0 + t], 1.0f);
  __syncthreads();  // b1

#pragma unroll
  for (int rr = 0; rr < 16; ++rr) {
    int row = wv * 16 + rr;
    float2 pv = *(const float2*)(pnode + ((size_t)b * cNP + n0 + row) * cF + lane * 2);
    unsigned avu = *(const unsigned*)(aggb + (((size_t)b * cNP + n0 + row) * cF + lane * 2));
    float ci_ = sm.cinv[row];
    float a0 = bf2f((u16)(avu & 0xffffu)) * ci_;
    float a1 = bf2f((u16)(avu >> 16)) * ci_;
    *(unsigned*)(sm.bufP + (size_t)row * SP + lane * 2) = pack2(pv.x, pv.y);
    *(unsigned*)(sm.bufX + (size_t)row * SP + lane * 2) = pack2(a0, a1);
  }
  __syncthreads();  // b2

  f32x4 acc[4][2];

  // ---- pnode L1: K=256 over [pf|mean] ----
  init_acc_s(acc, w.bp1, cw, l16);
  kloop128s(sm.bufP, wb + (size_t)G8_Wp1 * 1024, acc, cw, l16, quad);
  kloop128s(sm.bufX, wb + (size_t)(G8_Wp1 + 16) * 1024, acc, cw, l16, quad);
  __syncthreads();  // b3: all waves done reading bufX(mean)
  store_s<true>(sm.bufX, acc, cw, l16, quad);  // h1
  __syncthreads();  // b4

  // ---- pnode L2 + cond-norm(set2) + residual -> bufP ----
  init_acc_s(acc, w.bp2, cw, l16);
  kloop128s(sm.bufX, wb + (size_t)G8_Wp2 * 1024, acc, cw, l16, quad);
  cond_norm_s(acc, sm.red, sm.musig, ss + (size_t)(2 * cB + b) * 256, cw, l16, quad, wv, t);
#pragma unroll
  for (int ri = 0; ri < 4; ++ri)
#pragma unroll
    for (int reg = 0; reg < 4; ++reg) {
      int row = ri * 16 + quad * 4 + reg;
#pragma unroll
      for (int ci = 0; ci < 2; ++ci)
        acc[ri][ci][reg] += bf2f(sm.bufP[(size_t)row * SP + cw + ci * 16 + l16]);
    }
  __syncthreads();  // b5: all waves done residual-reading bufP
  store_s<false>(sm.bufP, acc, cw, l16, quad);  // p_new
  __syncthreads();  // b6

  // ---- output L1: K=128 -> bufX ----
  init_acc_s(acc, w.bo1, cw, l16);
  kloop128s(sm.bufP, wb + (size_t)G8_Wo1 * 1024, acc, cw, l16, quad);
  store_s<true>(sm.bufX, acc, cw, l16, quad);  // bufX reads ended before cond-norm barriers
  __syncthreads();  // b7

  // ---- output L2: K=128, N=4 (VALU, one output per thread) ----
  {
    int row = t >> 2, oc = t & 3;
    float a = w.bo2[oc];
    for (int k8 = 0; k8 < 16; ++k8) {
      s8v hv = *(const s8v*)(sm.bufX + (size_t)row * SP + k8 * 8);
#pragma unroll
      for (int j = 0; j < 8; ++j)
        a = fmaf(bf2f((u16)hv[j]), w.Wo2[(k8 * 8 + j) * 4 + oc], a);
    }
    out[((size_t)b * cNP + n0 + row) * 4 + oc] = a;
  }
}

// ---------------- launch ----------------
extern "C" void kernel_launch(void* const* d_in, const int* in_sizes, int n_in,
                              void* d_out, int out_size, void* d_ws, size_t ws_size,
                              hipStream_t stream) {
  const float* rnode = (const float*)d_in[0];
  const float* pnode = (const float*)d_in[1];
  const float* efeat = (const float*)d_in[2];
  const float* tau   = (const float*)d_in[3];
  const int* senders   = (const int*)d_in[40];
  const int* receivers = (const int*)d_in[41];
  float* ws = (float*)d_ws;
  u16* aggb = (u16*)d_ws;                 // bf16 [B][NP][128]
  u16* wb   = (u16*)(ws + WS_WB);

  SwzSrc sw;
  sw.p[0] = (const float*)d_in[5];   // We2
  sw.p[1] = (const float*)d_in[12];  // Wu1
  sw.p[2] = (const float*)d_in[13];  // Wu2
  sw.p[3] = (const float*)d_in[20];  // Wp1
  sw.p[4] = (const float*)d_in[21];  // Wp2
  sw.p[5] = (const float*)d_in[36];  // Wo1
  swz_kernel<<<(G8_TOT * 128 + 255) / 256, 256, 0, stream>>>(sw, wb);

  cond_kernel<<<dim3(3, cB), 256, 0, stream>>>(
      tau,
      (const float*)d_in[8],  (const float*)d_in[10],
      (const float*)d_in[9],  (const float*)d_in[11],
      (const float*)d_in[16], (const float*)d_in[18],
      (const float*)d_in[17], (const float*)d_in[19],
      (const float*)d_in[24], (const float*)d_in[26],
      (const float*)d_in[25], (const float*)d_in[27],
      ws + WS_SS);

  EWb ew = { (const float*)d_in[4], (const float*)d_in[6], (const float*)d_in[7],
             (const float*)d_in[14], (const float*)d_in[15] };   // We1, be1, be2, bu1, bu2
  PWb pw = { (const float*)d_in[22], (const float*)d_in[23], (const float*)d_in[38],
             (const float*)d_in[37], (const float*)d_in[39] };   // bp1, bp2, bo1, Wo2, bo2

  const int n4 = (int)(WS_SS / 4);
  zero_kernel<<<(n4 + 255) / 256, 256, 0, stream>>>((float4*)ws, n4);

  edge_mfma<<<dim3(cE / 64, cB), 256, 0, stream>>>(
      rnode, pnode, efeat, senders, receivers, ew, wb,
      ws + WS_SS, aggb, ws + WS_CNT);

  pnode_mfma<<<dim3(cNP / 64, cB), 256, 0, stream>>>(
      pnode, pw, wb, ws + WS_SS, aggb, ws + WS_CNT,
      (float*)d_out);
}

// Round 10
// 565.744 us; speedup vs baseline: 4.3773x; 1.0628x over previous
//
#include <hip/hip_runtime.h>

// ---------------- problem constants ----------------
constexpr int cB  = 2;
constexpr int cNR = 16384;
constexpr int cNP = 65536;
constexpr int cE  = 262144;
constexpr int cF  = 128;
constexpr int SP  = 136;   // bf16 row stride in LDS (2-way bank aliasing = free)

typedef unsigned short u16;
using f32x4 = __attribute__((ext_vector_type(4))) float;
using s8v   = __attribute__((ext_vector_type(8))) short;

// ws layout: agg bf16 [B][NP][128] (32 MB), cnt f32 [B][NP], ss, swizzled weights
constexpr size_t WS_CNT = ((size_t)cB * cNP * cF) / 2;
constexpr size_t WS_SS  = WS_CNT + (size_t)cB * cNP;
constexpr size_t WS_WB  = WS_SS + 3 * cB * 256;

// swizzled-weight segment bases (units of k8 = 8 K-rows; one k8 = 1024 u16)
constexpr int G8_We2 = 0, G8_Wu1 = 16, G8_Wu2 = 64, G8_Wp1 = 80, G8_Wp2 = 112, G8_Wo1 = 128;
constexpr int G8_TOT = 144;
// Wo2 (K=128, N=16-padded) lives after: 16 k8-blocks x [16][8] = 2048 u16
constexpr int SWZ_N = G8_TOT * 128 + 256;

// ---------------- helpers ----------------
__device__ __forceinline__ float bf2f(u16 u) {
  union { unsigned int i; float f; } v; v.i = ((unsigned int)u) << 16; return v.f;
}
__device__ __forceinline__ u16 f2bf(float f) {        // RNE (weights only)
  union { float f; unsigned int i; } v; v.f = f;
  unsigned int x = v.i;
  return (u16)((x + 0x7fffu + ((x >> 16) & 1u)) >> 16);
}
// fast round-half-up bf16 (intermediates; 2 VALU ops)
__device__ __forceinline__ u16 f2bf_fast(float f) {
  return (u16)((__float_as_uint(f) + 0x8000u) >> 16);
}
// packed pair via v_perm_b32 (3 VALU ops total)
__device__ __forceinline__ unsigned pack2(float a, float b) {
  return __builtin_amdgcn_perm(__float_as_uint(b) + 0x8000u,
                               __float_as_uint(a) + 0x8000u, 0x07060302u);
}
__device__ __forceinline__ float swishf(float x) { return x / (1.0f + __expf(-x)); }

// DPP add: x += dpp<CTRL>(x). Pure VALU (no LGKM). CTRL must be constexpr.
template <int CTRL>
__device__ __forceinline__ float dpp_add(float x) {
  int xi = __float_as_int(x);
  int r = __builtin_amdgcn_update_dpp(xi, xi, CTRL, 0xf, 0xf, false);
  return x + __int_as_float(r);
}
// value of lane^1 via DPP quad_perm(1,0,3,2)
__device__ __forceinline__ float dpp_xor1(float x) {
  int xi = __float_as_int(x);
  int r = __builtin_amdgcn_update_dpp(xi, xi, 0xB1, 0xf, 0xf, false);
  return __int_as_float(r);
}

// packed bf16x2 atomic add (global_atomic_pk_add_bf16, gfx950)
__device__ __forceinline__ void atomic_pk_bf16(u16* addr, float lo, float hi) {
  unsigned data = pack2(lo, hi);
  unsigned long long a = (unsigned long long)addr;
  asm volatile("global_atomic_pk_add_bf16 %0, %1, off" :: "v"(a), "v"(data) : "memory");
}

// ---- column-strip MFMA pass: wave covers rows 0..63 x 32-col strip (cw) ----
__device__ __forceinline__ void kloop128s(const u16* act, const u16* __restrict__ wbg,
                                          f32x4 (&acc)[4][2], int cw, int l16, int quad) {
  s8v bf[4][2];
#pragma unroll
  for (int k0 = 0; k0 < 4; ++k0)
#pragma unroll
    for (int ci = 0; ci < 2; ++ci)
      bf[k0][ci] = *(const s8v*)(wbg + ((size_t)(k0 * 4 + quad) * 128 + cw + ci * 16 + l16) * 8);
#pragma unroll
  for (int k0 = 0; k0 < 4; ++k0) {
    s8v af[4];
#pragma unroll
    for (int ri = 0; ri < 4; ++ri)
      af[ri] = *(const s8v*)(act + (size_t)(ri * 16 + l16) * SP + k0 * 32 + quad * 8);
#pragma unroll
    for (int ri = 0; ri < 4; ++ri)
#pragma unroll
      for (int ci = 0; ci < 2; ++ci)
        acc[ri][ci] = __builtin_amdgcn_mfma_f32_16x16x32_bf16(af[ri], bf[k0][ci], acc[ri][ci], 0, 0, 0);
  }
}

__device__ __forceinline__ void init_acc_s(f32x4 (&acc)[4][2], const float* __restrict__ bias,
                                           int cw, int l16) {
#pragma unroll
  for (int ci = 0; ci < 2; ++ci) {
    float bv = bias[cw + ci * 16 + l16];
#pragma unroll
    for (int ri = 0; ri < 4; ++ri) acc[ri][ci] = (f32x4){bv, bv, bv, bv};
  }
}

// conditioned LayerNorm on strip C-layout; 16-lane reduce via DPP row_ror (VALU only)
__device__ __forceinline__ void cond_norm_s(f32x4 (&acc)[4][2], float* red, float* musig,
                                            const float* __restrict__ ssp,
                                            int cw, int l16, int quad, int wv, int t) {
  __syncthreads();                 // prior LDS reads done; red/musig reuse safe
#pragma unroll
  for (int ri = 0; ri < 4; ++ri)
#pragma unroll
    for (int reg = 0; reg < 4; ++reg) {
      float v0 = acc[ri][0][reg], v1 = acc[ri][1][reg];
      float s = v0 + v1;
      float q = v0 * v0 + v1 * v1;
      s = dpp_add<0x128>(s); q = dpp_add<0x128>(q);   // row_ror:8
      s = dpp_add<0x124>(s); q = dpp_add<0x124>(q);   // row_ror:4
      s = dpp_add<0x122>(s); q = dpp_add<0x122>(q);   // row_ror:2
      s = dpp_add<0x121>(s); q = dpp_add<0x121>(q);   // row_ror:1
      if (l16 == 0) {
        int row = ri * 16 + quad * 4 + reg;
        red[row * 8 + wv * 2]     = s;
        red[row * 8 + wv * 2 + 1] = q;
      }
    }
  __syncthreads();
  if (t < 64) {
    float sum = red[t * 8 + 0] + red[t * 8 + 2] + red[t * 8 + 4] + red[t * 8 + 6];
    float sq  = red[t * 8 + 1] + red[t * 8 + 3] + red[t * 8 + 5] + red[t * 8 + 7];
    float mu  = sum * (1.0f / 128.0f);
    float var = fmaxf(sq * (1.0f / 128.0f) - mu * mu, 0.0f);
    musig[t * 2]     = mu;
    musig[t * 2 + 1] = rsqrtf(var + 1e-6f);
  }
  __syncthreads();
  float scl[2], shf[2];
#pragma unroll
  for (int ci = 0; ci < 2; ++ci) {
    int col = cw + ci * 16 + l16;
    scl[ci] = 1.0f + ssp[col];
    shf[ci] = ssp[128 + col];
  }
#pragma unroll
  for (int ri = 0; ri < 4; ++ri)
#pragma unroll
    for (int reg = 0; reg < 4; ++reg) {
      int row = ri * 16 + quad * 4 + reg;
      float mu = musig[row * 2], is = musig[row * 2 + 1];
#pragma unroll
      for (int ci = 0; ci < 2; ++ci)
        acc[ri][ci][reg] = (acc[ri][ci][reg] - mu) * is * scl[ci] + shf[ci];
    }
}

template <bool DOSWISH>
__device__ __forceinline__ void store_s(u16* buf, const f32x4 (&acc)[4][2],
                                        int cw, int l16, int quad) {
#pragma unroll
  for (int ri = 0; ri < 4; ++ri)
#pragma unroll
    for (int reg = 0; reg < 4; ++reg) {
      int row = ri * 16 + quad * 4 + reg;
#pragma unroll
      for (int ci = 0; ci < 2; ++ci) {
        float v = acc[ri][ci][reg];
        if (DOSWISH) v = swishf(v);
        buf[(size_t)row * SP + cw + ci * 16 + l16] = f2bf_fast(v);
      }
    }
}

// ---------------- kernel: zero agg (bf16) + cnt (f32) ----------------
__global__ void zero_kernel(float4* __restrict__ p, int n4) {
  int i = blockIdx.x * 256 + threadIdx.x;
  if (i < n4) p[i] = make_float4(0.f, 0.f, 0.f, 0.f);
}

// ---------------- kernel: weight bf16 swizzle ----------------
// main: W[K][128] -> [K/8][128][8] ; tail: Wo2[128][4] -> N=16-padded [16 k8][16][8]
struct SwzSrc { const float* p[6]; };  // We2, Wu1, Wu2, Wp1, Wp2, Wo1

__global__ void swz_kernel(SwzSrc s, const float* __restrict__ Wo2, u16* __restrict__ wb) {
  int t = blockIdx.x * 256 + threadIdx.x;
  if (t >= SWZ_N) return;
  if (t >= G8_TOT * 128) {
    int idx2 = t - G8_TOT * 128;
    int k8 = idx2 >> 4, n = idx2 & 15;
    u16 v[8];
#pragma unroll
    for (int j = 0; j < 8; ++j)
      v[j] = (n < 4) ? f2bf(Wo2[(size_t)(k8 * 8 + j) * 4 + n]) : (u16)0;
    ((uint4*)wb)[G8_TOT * 128 + k8 * 16 + n] = *(uint4*)v;
    return;
  }
  int n = t & 127, g8 = t >> 7;
  int seg, base;
  if (g8 < G8_Wu1)      { seg = 0; base = G8_We2; }
  else if (g8 < G8_Wu2) { seg = 1; base = G8_Wu1; }
  else if (g8 < G8_Wp1) { seg = 2; base = G8_Wu2; }
  else if (g8 < G8_Wp2) { seg = 3; base = G8_Wp1; }
  else if (g8 < G8_Wo1) { seg = 4; base = G8_Wp2; }
  else                  { seg = 5; base = G8_Wo1; }
  const float* W = s.p[seg];
  int k8l = g8 - base;
  u16 v[8];
#pragma unroll
  for (int j = 0; j < 8; ++j) v[j] = f2bf(W[(size_t)(k8l * 8 + j) * 128 + n]);
  ((uint4*)wb)[g8 * 128 + n] = *(uint4*)v;
}

// ---------------- kernel: tau-conditioned scale/shift (3 sets) ----------------
__global__ void cond_kernel(const float* __restrict__ tau,
                            const float* __restrict__ Ce1, const float* __restrict__ ce1,
                            const float* __restrict__ Ce2, const float* __restrict__ ce2,
                            const float* __restrict__ Cu1, const float* __restrict__ cu1,
                            const float* __restrict__ Cu2, const float* __restrict__ cu2,
                            const float* __restrict__ Cp1, const float* __restrict__ cp1,
                            const float* __restrict__ Cp2, const float* __restrict__ cp2,
                            float* __restrict__ ss) {
  int set = blockIdx.x, b = blockIdx.y, j = threadIdx.x;
  const float *C1, *c1, *C2, *c2;
  if (set == 0)      { C1 = Ce1; c1 = ce1; C2 = Ce2; c2 = ce2; }
  else if (set == 1) { C1 = Cu1; c1 = cu1; C2 = Cu2; c2 = cu2; }
  else               { C1 = Cp1; c1 = cp1; C2 = Cp2; c2 = cp2; }
  float tf = tau[b];
  float a = c2[j];
  for (int k = 0; k < 16; ++k) {
    float h = swishf(tf * C1[k] + c1[k]);
    a = fmaf(h, C2[k * 256 + j], a);
  }
  ss[(size_t)set * cB * 256 + (size_t)b * 256 + j] = a;
}

// ---------------- fused MFMA edge pipeline (both batches), M=64 edges/block ----------------
struct EWb { const float *We1, *be1, *be2, *bu1, *bu2; };

struct __align__(16) EdgeSmem {
  u16 bufE[64 * SP];   // h_embed -> e_emb (kept for final residual)
  u16 bufX[64 * SP];   // sf -> rf -> h2
  float ef4[256];
  float red[512];
  float musig[128];
  int sidx[64], ridx[64];
};  // ~38.9 KB -> 4 blocks/CU

__global__ __launch_bounds__(256, 4) void edge_mfma(
    const float* __restrict__ rnode, const float* __restrict__ pnode,
    const float* __restrict__ efeat, const int* __restrict__ senders,
    const int* __restrict__ receivers, EWb w, const u16* __restrict__ wb,
    const float* __restrict__ ss, u16* __restrict__ aggb, float* __restrict__ cnt) {
  __shared__ EdgeSmem sm;
  const int t = threadIdx.x, wv = t >> 6, lane = t & 63, l16 = lane & 15, quad = lane >> 4;
  const int cw = wv * 32;          // column strip base
  const int b  = blockIdx.y;
  const int e0 = blockIdx.x * 64;

  if (t < 64) {
    sm.sidx[t] = min(max(senders[(size_t)b * cE + e0 + t], 0), cNR - 1);
    sm.ridx[t] = min(max(receivers[(size_t)b * cE + e0 + t], 0), cNP - 1);
  } else if (t >= 128) {
    ((float2*)sm.ef4)[t - 128] = ((const float2*)(efeat + ((size_t)b * cE + e0) * 4))[t - 128];
  }
  __syncthreads();  // b1

  // gather sf -> bufX now; rf -> registers (consumed after b4, latency hidden)
  unsigned rfp[16];
#pragma unroll
  for (int rr = 0; rr < 16; ++rr) {
    int row = wv * 16 + rr;
    float2 sv = *(const float2*)(rnode + ((size_t)b * cNR + sm.sidx[row]) * cF + lane * 2);
    float2 rv = *(const float2*)(pnode + ((size_t)b * cNP + sm.ridx[row]) * cF + lane * 2);
    *(unsigned*)(sm.bufX + (size_t)row * SP + lane * 2) = pack2(sv.x, sv.y);
    rfp[rr] = pack2(rv.x, rv.y);
  }

  // embed layer 1 (K=4, VALU) -> bufE
  {
    int col = t & 127, half = t >> 7;
    float w0 = w.We1[col], w1 = w.We1[128 + col], w2 = w.We1[256 + col], w3 = w.We1[384 + col];
    float bb = w.be1[col];
    for (int r = 0; r < 32; ++r) {
      int row = half * 32 + r;
      float a = fmaf(sm.ef4[row * 4 + 3], w3, fmaf(sm.ef4[row * 4 + 2], w2,
                fmaf(sm.ef4[row * 4 + 1], w1, fmaf(sm.ef4[row * 4 + 0], w0, bb))));
      sm.bufE[(size_t)row * SP + col] = f2bf_fast(swishf(a));
    }
  }
  __syncthreads();  // b2: bufE(h_embed) + bufX(sf) visible

  f32x4 acc[4][2];

  // ---- embed L2 + cond-norm(set0) -> e_emb (bufE) ----
  init_acc_s(acc, w.be2, cw, l16);
  kloop128s(sm.bufE, wb + (size_t)G8_We2 * 1024, acc, cw, l16, quad);
  cond_norm_s(acc, sm.red, sm.musig, ss + (size_t)b * 256, cw, l16, quad, wv, t);
  store_s<false>(sm.bufE, acc, cw, l16, quad);
  __syncthreads();  // b3: e_emb visible

  // ---- update L1: K=384 over [e|sf|rf] ----
  f32x4 accU[4][2];
  init_acc_s(accU, w.bu1, cw, l16);
  kloop128s(sm.bufE, wb + (size_t)G8_Wu1 * 1024, accU, cw, l16, quad);
  kloop128s(sm.bufX, wb + (size_t)(G8_Wu1 + 16) * 1024, accU, cw, l16, quad);
  __syncthreads();  // b4: all waves done reading bufX(sf)

  // spill prefetched rf regs -> bufX
#pragma unroll
  for (int rr = 0; rr < 16; ++rr)
    *(unsigned*)(sm.bufX + (size_t)(wv * 16 + rr) * SP + lane * 2) = rfp[rr];
  __syncthreads();  // b5: bufX(rf) visible

  kloop128s(sm.bufX, wb + (size_t)(G8_Wu1 + 32) * 1024, accU, cw, l16, quad);
  __syncthreads();  // b6: all waves done reading bufX(rf)
  store_s<true>(sm.bufX, accU, cw, l16, quad);  // h2
  __syncthreads();  // b7: h2 visible

  // ---- update L2 + cond-norm(set1) ----
  init_acc_s(acc, w.bu2, cw, l16);
  kloop128s(sm.bufX, wb + (size_t)G8_Wu2 * 1024, acc, cw, l16, quad);
  cond_norm_s(acc, sm.red, sm.musig, ss + (size_t)(cB + b) * 256, cw, l16, quad, wv, t);

  // e = e_emb + u ; packed-bf16 segment-sum atomics (even lane pairs with odd via DPP)
#pragma unroll
  for (int ri = 0; ri < 4; ++ri)
#pragma unroll
    for (int reg = 0; reg < 4; ++reg) {
      int row = ri * 16 + quad * 4 + reg;
      size_t rbase = ((size_t)b * cNP + sm.ridx[row]) * cF;
#pragma unroll
      for (int ci = 0; ci < 2; ++ci) {
        int col = cw + ci * 16 + l16;
        float v = acc[ri][ci][reg] + bf2f(sm.bufE[(size_t)row * SP + col]);
        float vo = dpp_xor1(v);
        if (!(lane & 1)) atomic_pk_bf16(aggb + rbase + col, v, vo);
      }
    }
  if (t < 64) atomicAdd(cnt + (size_t)b * cNP + sm.ridx[t], 1.0f);
}

// ---------------- fused MFMA pnode pipeline (both batches), M=64 nodes/block ----------------
struct PWb { const float *bp1, *bp2, *bo1, *bo2; };

struct __align__(16) PnodeSmem {
  u16 bufP[64 * SP];   // pf -> p_new
  u16 bufX[64 * SP];   // mean -> h1 -> h_out
  float red[512];
  float musig[128];
  float cinv[64];
};  // ~37.6 KB -> 4 blocks/CU

__global__ __launch_bounds__(256, 4) void pnode_mfma(
    const float* __restrict__ pnode, PWb w, const u16* __restrict__ wb,
    const float* __restrict__ ss, const u16* __restrict__ aggb,
    const float* __restrict__ cnt, float* __restrict__ out) {
  __shared__ PnodeSmem sm;
  const int t = threadIdx.x, wv = t >> 6, lane = t & 63, l16 = lane & 15, quad = lane >> 4;
  const int cw = wv * 32;
  const int b  = blockIdx.y;
  const int n0 = blockIdx.x * 64;

  if (t < 64) sm.cinv[t] = 1.0f / fmaxf(cnt[(size_t)b * cNP + n0 + t], 1.0f);
  __syncthreads();  // b1

#pragma unroll
  for (int rr = 0; rr < 16; ++rr) {
    int row = wv * 16 + rr;
    float2 pv = *(const float2*)(pnode + ((size_t)b * cNP + n0 + row) * cF + lane * 2);
    unsigned avu = *(const unsigned*)(aggb + (((size_t)b * cNP + n0 + row) * cF + lane * 2));
    float ci_ = sm.cinv[row];
    float a0 = bf2f((u16)(avu & 0xffffu)) * ci_;
    float a1 = bf2f((u16)(avu >> 16)) * ci_;
    *(unsigned*)(sm.bufP + (size_t)row * SP + lane * 2) = pack2(pv.x, pv.y);
    *(unsigned*)(sm.bufX + (size_t)row * SP + lane * 2) = pack2(a0, a1);
  }
  __syncthreads();  // b2

  f32x4 acc[4][2];

  // ---- pnode L1: K=256 over [pf|mean] ----
  init_acc_s(acc, w.bp1, cw, l16);
  kloop128s(sm.bufP, wb + (size_t)G8_Wp1 * 1024, acc, cw, l16, quad);
  kloop128s(sm.bufX, wb + (size_t)(G8_Wp1 + 16) * 1024, acc, cw, l16, quad);
  __syncthreads();  // b3: all waves done reading bufX(mean)
  store_s<true>(sm.bufX, acc, cw, l16, quad);  // h1
  __syncthreads();  // b4

  // ---- pnode L2 + cond-norm(set2) + residual -> bufP ----
  init_acc_s(acc, w.bp2, cw, l16);
  kloop128s(sm.bufX, wb + (size_t)G8_Wp2 * 1024, acc, cw, l16, quad);
  cond_norm_s(acc, sm.red, sm.musig, ss + (size_t)(2 * cB + b) * 256, cw, l16, quad, wv, t);
#pragma unroll
  for (int ri = 0; ri < 4; ++ri)
#pragma unroll
    for (int reg = 0; reg < 4; ++reg) {
      int row = ri * 16 + quad * 4 + reg;
#pragma unroll
      for (int ci = 0; ci < 2; ++ci)
        acc[ri][ci][reg] += bf2f(sm.bufP[(size_t)row * SP + cw + ci * 16 + l16]);
    }
  __syncthreads();  // b5: all waves done residual-reading bufP
  store_s<false>(sm.bufP, acc, cw, l16, quad);  // p_new
  __syncthreads();  // b6

  // ---- output L1: K=128 -> bufX ----
  init_acc_s(acc, w.bo1, cw, l16);
  kloop128s(sm.bufP, wb + (size_t)G8_Wo1 * 1024, acc, cw, l16, quad);
  store_s<true>(sm.bufX, acc, cw, l16, quad);  // bufX reads ended before cond-norm barriers
  __syncthreads();  // b7

  // ---- output L2 via MFMA: K=128, N=16 (4 used); wave wv owns rows wv*16..+15 ----
  {
    const u16* wo2 = wb + (size_t)G8_TOT * 1024;
    float bv = (l16 < 4) ? w.bo2[l16] : 0.0f;
    f32x4 a1 = {bv, bv, bv, bv};
#pragma unroll
    for (int k0 = 0; k0 < 4; ++k0) {
      s8v af = *(const s8v*)(sm.bufX + (size_t)(wv * 16 + l16) * SP + k0 * 32 + quad * 8);
      s8v bf = *(const s8v*)(wo2 + ((size_t)(k0 * 4 + quad) * 16 + l16) * 8);
      a1 = __builtin_amdgcn_mfma_f32_16x16x32_bf16(af, bf, a1, 0, 0, 0);
    }
    if (l16 < 4) {
      size_t obase = (size_t)b * cNP + n0 + wv * 16 + quad * 4;
#pragma unroll
      for (int reg = 0; reg < 4; ++reg)
        out[(obase + reg) * 4 + l16] = a1[reg];
    }
  }
}

// ---------------- launch ----------------
extern "C" void kernel_launch(void* const* d_in, const int* in_sizes, int n_in,
                              void* d_out, int out_size, void* d_ws, size_t ws_size,
                              hipStream_t stream) {
  const float* rnode = (const float*)d_in[0];
  const float* pnode = (const float*)d_in[1];
  const float* efeat = (const float*)d_in[2];
  const float* tau   = (const float*)d_in[3];
  const int* senders   = (const int*)d_in[40];
  const int* receivers = (const int*)d_in[41];
  float* ws = (float*)d_ws;
  u16* aggb = (u16*)d_ws;                 // bf16 [B][NP][128]
  u16* wb   = (u16*)(ws + WS_WB);

  SwzSrc sw;
  sw.p[0] = (const float*)d_in[5];   // We2
  sw.p[1] = (const float*)d_in[12];  // Wu1
  sw.p[2] = (const float*)d_in[13];  // Wu2
  sw.p[3] = (const float*)d_in[20];  // Wp1
  sw.p[4] = (const float*)d_in[21];  // Wp2
  sw.p[5] = (const float*)d_in[36];  // Wo1
  swz_kernel<<<(SWZ_N + 255) / 256, 256, 0, stream>>>(sw, (const float*)d_in[37], wb);

  cond_kernel<<<dim3(3, cB), 256, 0, stream>>>(
      tau,
      (const float*)d_in[8],  (const float*)d_in[10],
      (const float*)d_in[9],  (const float*)d_in[11],
      (const float*)d_in[16], (const float*)d_in[18],
      (const float*)d_in[17], (const float*)d_in[19],
      (const float*)d_in[24], (const float*)d_in[26],
      (const float*)d_in[25], (const float*)d_in[27],
      ws + WS_SS);

  EWb ew = { (const float*)d_in[4], (const float*)d_in[6], (const float*)d_in[7],
             (const float*)d_in[14], (const float*)d_in[15] };   // We1, be1, be2, bu1, bu2
  PWb pw = { (const float*)d_in[22], (const float*)d_in[23], (const float*)d_in[38],
             (const float*)d_in[39] };                            // bp1, bp2, bo1, bo2

  const int n4 = (int)(WS_SS / 4);
  zero_kernel<<<(n4 + 255) / 256, 256, 0, stream>>>((float4*)ws, n4);

  edge_mfma<<<dim3(cE / 64, cB), 256, 0, stream>>>(
      rnode, pnode, efeat, senders, receivers, ew, wb,
      ws + WS_SS, aggb, ws + WS_CNT);

  pnode_mfma<<<dim3(cNP / 64, cB), 256, 0, stream>>>(
      pnode, pw, wb, ws + WS_SS, aggb, ws + WS_CNT,
      (float*)d_out);
}

// Round 12
// 565.403 us; speedup vs baseline: 4.3799x; 1.0006x over previous
//
#include <hip/hip_runtime.h>

// ---------------- problem constants ----------------
constexpr int cB  = 2;
constexpr int cNR = 16384;
constexpr int cNP = 65536;
constexpr int cE  = 262144;
constexpr int cF  = 128;
constexpr int SP  = 136;   // bf16 row stride in LDS (2-way bank aliasing = free)

typedef unsigned short u16;
using f32x4 = __attribute__((ext_vector_type(4))) float;
using s8v   = __attribute__((ext_vector_type(8))) short;

// ws layout (float offsets): agg bf16 [B][NP][128] (33.5 MB), cnt f32 [B][NP],
// ss (3x[B,256]), swizzled weights (SWZ_N*8 u16 = 299 KB), rnode_bf16 (8.4 MB).
constexpr size_t WS_CNT = ((size_t)cB * cNP * cF) / 2;
constexpr size_t WS_SS  = WS_CNT + (size_t)cB * cNP;
constexpr size_t WS_WB  = WS_SS + 3 * cB * 256;

// swizzled-weight segment bases (units of k8 = 8 K-rows; one k8 = 1024 u16)
constexpr int G8_We2 = 0, G8_Wu1 = 16, G8_Wu2 = 64, G8_Wp1 = 80, G8_Wp2 = 112, G8_Wo1 = 128;
constexpr int G8_TOT = 144;
// Wo2 (K=128, N=16-padded) after: 16 k8-blocks x [16][8] = 2048 u16
constexpr int SWZ_N = G8_TOT * 128 + 256;            // uint4 elements (threads)
// rnode bf16 copy AFTER the full weight buffer: SWZ_N uint4 = SWZ_N*8 u16 = SWZ_N*4 floats
constexpr size_t WS_RB = WS_WB + (size_t)SWZ_N * 4;

// ---------------- helpers ----------------
__device__ __forceinline__ float bf2f(u16 u) {
  union { unsigned int i; float f; } v; v.i = ((unsigned int)u) << 16; return v.f;
}
__device__ __forceinline__ u16 f2bf(float f) {        // RNE (weights only)
  union { float f; unsigned int i; } v; v.f = f;
  unsigned int x = v.i;
  return (u16)((x + 0x7fffu + ((x >> 16) & 1u)) >> 16);
}
// fast round-half-up bf16 (intermediates; 2 VALU ops)
__device__ __forceinline__ u16 f2bf_fast(float f) {
  return (u16)((__float_as_uint(f) + 0x8000u) >> 16);
}
// packed pair via v_perm_b32 (3 VALU ops total)
__device__ __forceinline__ unsigned pack2(float a, float b) {
  return __builtin_amdgcn_perm(__float_as_uint(b) + 0x8000u,
                               __float_as_uint(a) + 0x8000u, 0x07060302u);
}
// swish via single v_rcp_f32 (1-ulp) instead of precise-divide sequence (~10 ops)
__device__ __forceinline__ float swishf(float x) {
  return x * __builtin_amdgcn_rcpf(1.0f + __expf(-x));
}

// DPP add: x += dpp<CTRL>(x). Pure VALU (no LGKM). CTRL must be constexpr.
template <int CTRL>
__device__ __forceinline__ float dpp_add(float x) {
  int xi = __float_as_int(x);
  int r = __builtin_amdgcn_update_dpp(xi, xi, CTRL, 0xf, 0xf, false);
  return x + __int_as_float(r);
}
// value of lane^1 via DPP quad_perm(1,0,3,2)
__device__ __forceinline__ float dpp_xor1(float x) {
  int xi = __float_as_int(x);
  int r = __builtin_amdgcn_update_dpp(xi, xi, 0xB1, 0xf, 0xf, false);
  return __int_as_float(r);
}

// packed bf16x2 atomic add (global_atomic_pk_add_bf16, gfx950)
__device__ __forceinline__ void atomic_pk_bf16(u16* addr, float lo, float hi) {
  unsigned data = pack2(lo, hi);
  unsigned long long a = (unsigned long long)addr;
  asm volatile("global_atomic_pk_add_bf16 %0, %1, off" :: "v"(a), "v"(data) : "memory");
}

// ---- column-strip MFMA pass: wave covers rows 0..63 x 32-col strip (cw) ----
__device__ __forceinline__ void kloop128s(const u16* act, const u16* __restrict__ wbg,
                                          f32x4 (&acc)[4][2], int cw, int l16, int quad) {
  s8v bf[4][2];
#pragma unroll
  for (int k0 = 0; k0 < 4; ++k0)
#pragma unroll
    for (int ci = 0; ci < 2; ++ci)
      bf[k0][ci] = *(const s8v*)(wbg + ((size_t)(k0 * 4 + quad) * 128 + cw + ci * 16 + l16) * 8);
#pragma unroll
  for (int k0 = 0; k0 < 4; ++k0) {
    s8v af[4];
#pragma unroll
    for (int ri = 0; ri < 4; ++ri)
      af[ri] = *(const s8v*)(act + (size_t)(ri * 16 + l16) * SP + k0 * 32 + quad * 8);
#pragma unroll
    for (int ri = 0; ri < 4; ++ri)
#pragma unroll
      for (int ci = 0; ci < 2; ++ci)
        acc[ri][ci] = __builtin_amdgcn_mfma_f32_16x16x32_bf16(af[ri], bf[k0][ci], acc[ri][ci], 0, 0, 0);
  }
}

__device__ __forceinline__ void init_acc_s(f32x4 (&acc)[4][2], const float* __restrict__ bias,
                                           int cw, int l16) {
#pragma unroll
  for (int ci = 0; ci < 2; ++ci) {
    float bv = bias[cw + ci * 16 + l16];
#pragma unroll
    for (int ri = 0; ri < 4; ++ri) acc[ri][ci] = (f32x4){bv, bv, bv, bv};
  }
}

// conditioned LayerNorm on strip C-layout; 16-lane reduce via DPP row_ror (VALU only)
__device__ __forceinline__ void cond_norm_s(f32x4 (&acc)[4][2], float* red, float* musig,
                                            const float* __restrict__ ssp,
                                            int cw, int l16, int quad, int wv, int t) {
  __syncthreads();                 // prior LDS reads done; red/musig reuse safe
#pragma unroll
  for (int ri = 0; ri < 4; ++ri)
#pragma unroll
    for (int reg = 0; reg < 4; ++reg) {
      float v0 = acc[ri][0][reg], v1 = acc[ri][1][reg];
      float s = v0 + v1;
      float q = v0 * v0 + v1 * v1;
      s = dpp_add<0x128>(s); q = dpp_add<0x128>(q);   // row_ror:8
      s = dpp_add<0x124>(s); q = dpp_add<0x124>(q);   // row_ror:4
      s = dpp_add<0x122>(s); q = dpp_add<0x122>(q);   // row_ror:2
      s = dpp_add<0x121>(s); q = dpp_add<0x121>(q);   // row_ror:1
      if (l16 == 0) {
        int row = ri * 16 + quad * 4 + reg;
        red[row * 8 + wv * 2]     = s;
        red[row * 8 + wv * 2 + 1] = q;
      }
    }
  __syncthreads();
  if (t < 64) {
    float sum = red[t * 8 + 0] + red[t * 8 + 2] + red[t * 8 + 4] + red[t * 8 + 6];
    float sq  = red[t * 8 + 1] + red[t * 8 + 3] + red[t * 8 + 5] + red[t * 8 + 7];
    float mu  = sum * (1.0f / 128.0f);
    float var = fmaxf(sq * (1.0f / 128.0f) - mu * mu, 0.0f);
    musig[t * 2]     = mu;
    musig[t * 2 + 1] = __builtin_amdgcn_rsqf(var + 1e-6f);
  }
  __syncthreads();
  float scl[2], shf[2];
#pragma unroll
  for (int ci = 0; ci < 2; ++ci) {
    int col = cw + ci * 16 + l16;
    scl[ci] = 1.0f + ssp[col];
    shf[ci] = ssp[128 + col];
  }
#pragma unroll
  for (int ri = 0; ri < 4; ++ri)
#pragma unroll
    for (int reg = 0; reg < 4; ++reg) {
      int row = ri * 16 + quad * 4 + reg;
      float mu = musig[row * 2], is = musig[row * 2 + 1];
#pragma unroll
      for (int ci = 0; ci < 2; ++ci)
        acc[ri][ci][reg] = (acc[ri][ci][reg] - mu) * is * scl[ci] + shf[ci];
    }
}

template <bool DOSWISH>
__device__ __forceinline__ void store_s(u16* buf, const f32x4 (&acc)[4][2],
                                        int cw, int l16, int quad) {
#pragma unroll
  for (int ri = 0; ri < 4; ++ri)
#pragma unroll
    for (int reg = 0; reg < 4; ++reg) {
      int row = ri * 16 + quad * 4 + reg;
#pragma unroll
      for (int ci = 0; ci < 2; ++ci) {
        float v = acc[ri][ci][reg];
        if (DOSWISH) v = swishf(v);
        buf[(size_t)row * SP + cw + ci * 16 + l16] = f2bf_fast(v);
      }
    }
}

// ---------------- kernel: zero agg (bf16) + cnt (f32) ----------------
__global__ void zero_kernel(float4* __restrict__ p, int n4) {
  int i = blockIdx.x * 256 + threadIdx.x;
  if (i < n4) p[i] = make_float4(0.f, 0.f, 0.f, 0.f);
}

// ---------------- kernel: rnode f32 -> bf16 copy ----------------
__global__ void cvtn_kernel(const float* __restrict__ src, u16* __restrict__ dst, int n2) {
  int i = blockIdx.x * 256 + threadIdx.x;   // u32-pair index
  if (i >= n2) return;
  float2 v = ((const float2*)src)[i];
  ((unsigned*)dst)[i] = pack2(v.x, v.y);
}

// ---------------- kernel: weight bf16 swizzle ----------------
// main: W[K][128] -> [K/8][128][8] ; tail: Wo2[128][4] -> N=16-padded [16 k8][16][8]
struct SwzSrc { const float* p[6]; };  // We2, Wu1, Wu2, Wp1, Wp2, Wo1

__global__ void swz_kernel(SwzSrc s, const float* __restrict__ Wo2, u16* __restrict__ wb) {
  int t = blockIdx.x * 256 + threadIdx.x;
  if (t >= SWZ_N) return;
  if (t >= G8_TOT * 128) {
    int idx2 = t - G8_TOT * 128;
    int k8 = idx2 >> 4, n = idx2 & 15;
    u16 v[8];
#pragma unroll
    for (int j = 0; j < 8; ++j)
      v[j] = (n < 4) ? f2bf(Wo2[(size_t)(k8 * 8 + j) * 4 + n]) : (u16)0;
    ((uint4*)wb)[G8_TOT * 128 + k8 * 16 + n] = *(uint4*)v;
    return;
  }
  int n = t & 127, g8 = t >> 7;
  int seg, base;
  if (g8 < G8_Wu1)      { seg = 0; base = G8_We2; }
  else if (g8 < G8_Wu2) { seg = 1; base = G8_Wu1; }
  else if (g8 < G8_Wp1) { seg = 2; base = G8_Wu2; }
  else if (g8 < G8_Wp2) { seg = 3; base = G8_Wp1; }
  else if (g8 < G8_Wo1) { seg = 4; base = G8_Wp2; }
  else                  { seg = 5; base = G8_Wo1; }
  const float* W = s.p[seg];
  int k8l = g8 - base;
  u16 v[8];
#pragma unroll
  for (int j = 0; j < 8; ++j) v[j] = f2bf(W[(size_t)(k8l * 8 + j) * 128 + n]);
  ((uint4*)wb)[g8 * 128 + n] = *(uint4*)v;
}

// ---------------- kernel: tau-conditioned scale/shift (3 sets) ----------------
__global__ void cond_kernel(const float* __restrict__ tau,
                            const float* __restrict__ Ce1, const float* __restrict__ ce1,
                            const float* __restrict__ Ce2, const float* __restrict__ ce2,
                            const float* __restrict__ Cu1, const float* __restrict__ cu1,
                            const float* __restrict__ Cu2, const float* __restrict__ cu2,
                            const float* __restrict__ Cp1, const float* __restrict__ cp1,
                            const float* __restrict__ Cp2, const float* __restrict__ cp2,
                            float* __restrict__ ss) {
  int set = blockIdx.x, b = blockIdx.y, j = threadIdx.x;
  const float *C1, *c1, *C2, *c2;
  if (set == 0)      { C1 = Ce1; c1 = ce1; C2 = Ce2; c2 = ce2; }
  else if (set == 1) { C1 = Cu1; c1 = cu1; C2 = Cu2; c2 = cu2; }
  else               { C1 = Cp1; c1 = cp1; C2 = Cp2; c2 = cp2; }
  float tf = tau[b];
  float a = c2[j];
  for (int k = 0; k < 16; ++k) {
    float h = swishf(tf * C1[k] + c1[k]);
    a = fmaf(h, C2[k * 256 + j], a);
  }
  ss[(size_t)set * cB * 256 + (size_t)b * 256 + j] = a;
}

// ---------------- fused MFMA edge pipeline (both batches), M=64 edges/block ----------------
struct EWb { const float *We1, *be1, *be2, *bu1, *bu2; };

struct __align__(16) EdgeSmem {
  u16 bufE[64 * SP];   // h_embed -> e_emb (kept for final residual)
  u16 bufX[64 * SP];   // sf -> rf -> h2
  float ef4[256];
  float red[512];
  float musig[128];
  int sidx[64], ridx[64];
};  // ~38.9 KB -> 4 blocks/CU

__global__ __launch_bounds__(256, 4) void edge_mfma(
    const u16* __restrict__ rnb, const float* __restrict__ pnode,
    const float* __restrict__ efeat, const int* __restrict__ senders,
    const int* __restrict__ receivers, EWb w, const u16* __restrict__ wb,
    const float* __restrict__ ss, u16* __restrict__ aggb, float* __restrict__ cnt) {
  __shared__ EdgeSmem sm;
  const int t = threadIdx.x, wv = t >> 6, lane = t & 63, l16 = lane & 15, quad = lane >> 4;
  const int cw = wv * 32;          // column strip base
  const int b  = blockIdx.y;
  const int e0 = blockIdx.x * 64;

  if (t < 64) {
    sm.sidx[t] = min(max(senders[(size_t)b * cE + e0 + t], 0), cNR - 1);
    sm.ridx[t] = min(max(receivers[(size_t)b * cE + e0 + t], 0), cNP - 1);
  } else if (t >= 128) {
    ((float2*)sm.ef4)[t - 128] = ((const float2*)(efeat + ((size_t)b * cE + e0) * 4))[t - 128];
  }
  __syncthreads();  // b1

  // gather sf (bf16 pre-converted, u32 copy) -> bufX; rf -> registers
  unsigned rfp[16];
#pragma unroll
  for (int rr = 0; rr < 16; ++rr) {
    int row = wv * 16 + rr;
    unsigned sv = *(const unsigned*)(rnb + ((size_t)b * cNR + sm.sidx[row]) * cF + lane * 2);
    float2 rv = *(const float2*)(pnode + ((size_t)b * cNP + sm.ridx[row]) * cF + lane * 2);
    *(unsigned*)(sm.bufX + (size_t)row * SP + lane * 2) = sv;
    rfp[rr] = pack2(rv.x, rv.y);
  }

  // embed layer 1 (K=4, VALU) -> bufE
  {
    int col = t & 127, half = t >> 7;
    float w0 = w.We1[col], w1 = w.We1[128 + col], w2 = w.We1[256 + col], w3 = w.We1[384 + col];
    float bb = w.be1[col];
    for (int r = 0; r < 32; ++r) {
      int row = half * 32 + r;
      float a = fmaf(sm.ef4[row * 4 + 3], w3, fmaf(sm.ef4[row * 4 + 2], w2,
                fmaf(sm.ef4[row * 4 + 1], w1, fmaf(sm.ef4[row * 4 + 0], w0, bb))));
      sm.bufE[(size_t)row * SP + col] = f2bf_fast(swishf(a));
    }
  }
  __syncthreads();  // b2: bufE(h_embed) + bufX(sf) visible

  f32x4 acc[4][2];

  // ---- embed L2 + cond-norm(set0) -> e_emb (bufE) ----
  init_acc_s(acc, w.be2, cw, l16);
  kloop128s(sm.bufE, wb + (size_t)G8_We2 * 1024, acc, cw, l16, quad);
  cond_norm_s(acc, sm.red, sm.musig, ss + (size_t)b * 256, cw, l16, quad, wv, t);
  store_s<false>(sm.bufE, acc, cw, l16, quad);
  __syncthreads();  // b3: e_emb visible

  // ---- update L1: K=384 over [e|sf|rf] ----
  f32x4 accU[4][2];
  init_acc_s(accU, w.bu1, cw, l16);
  kloop128s(sm.bufE, wb + (size_t)G8_Wu1 * 1024, accU, cw, l16, quad);
  kloop128s(sm.bufX, wb + (size_t)(G8_Wu1 + 16) * 1024, accU, cw, l16, quad);
  __syncthreads();  // b4: all waves done reading bufX(sf)

  // spill prefetched rf regs -> bufX
#pragma unroll
  for (int rr = 0; rr < 16; ++rr)
    *(unsigned*)(sm.bufX + (size_t)(wv * 16 + rr) * SP + lane * 2) = rfp[rr];
  __syncthreads();  // b5: bufX(rf) visible

  kloop128s(sm.bufX, wb + (size_t)(G8_Wu1 + 32) * 1024, accU, cw, l16, quad);
  __syncthreads();  // b6: all waves done reading bufX(rf)
  store_s<true>(sm.bufX, accU, cw, l16, quad);  // h2
  __syncthreads();  // b7: h2 visible

  // ---- update L2 + cond-norm(set1) ----
  init_acc_s(acc, w.bu2, cw, l16);
  kloop128s(sm.bufX, wb + (size_t)G8_Wu2 * 1024, acc, cw, l16, quad);
  cond_norm_s(acc, sm.red, sm.musig, ss + (size_t)(cB + b) * 256, cw, l16, quad, wv, t);

  // e = e_emb + u ; packed-bf16 segment-sum atomics (even lane pairs with odd via DPP)
#pragma unroll
  for (int ri = 0; ri < 4; ++ri)
#pragma unroll
    for (int reg = 0; reg < 4; ++reg) {
      int row = ri * 16 + quad * 4 + reg;
      size_t rbase = ((size_t)b * cNP + sm.ridx[row]) * cF;
#pragma unroll
      for (int ci = 0; ci < 2; ++ci) {
        int col = cw + ci * 16 + l16;
        float v = acc[ri][ci][reg] + bf2f(sm.bufE[(size_t)row * SP + col]);
        float vo = dpp_xor1(v);
        if (!(lane & 1)) atomic_pk_bf16(aggb + rbase + col, v, vo);
      }
    }
  if (t < 64) atomicAdd(cnt + (size_t)b * cNP + sm.ridx[t], 1.0f);
}

// ---------------- fused MFMA pnode pipeline (both batches), M=64 nodes/block ----------------
struct PWb { const float *bp1, *bp2, *bo1, *bo2; };

struct __align__(16) PnodeSmem {
  u16 bufP[64 * SP];   // pf -> p_new
  u16 bufX[64 * SP];   // mean -> h1 -> h_out
  float red[512];
  float musig[128];
  float cinv[64];
};  // ~37.6 KB -> 4 blocks/CU

__global__ __launch_bounds__(256, 4) void pnode_mfma(
    const float* __restrict__ pnode, PWb w, const u16* __restrict__ wb,
    const float* __restrict__ ss, const u16* __restrict__ aggb,
    const float* __restrict__ cnt, float* __restrict__ out) {
  __shared__ PnodeSmem sm;
  const int t = threadIdx.x, wv = t >> 6, lane = t & 63, l16 = lane & 15, quad = lane >> 4;
  const int cw = wv * 32;
  const int b  = blockIdx.y;
  const int n0 = blockIdx.x * 64;

  if (t < 64) sm.cinv[t] = __builtin_amdgcn_rcpf(fmaxf(cnt[(size_t)b * cNP + n0 + t], 1.0f));
  __syncthreads();  // b1

#pragma unroll
  for (int rr = 0; rr < 16; ++rr) {
    int row = wv * 16 + rr;
    float2 pv = *(const float2*)(pnode + ((size_t)b * cNP + n0 + row) * cF + lane * 2);
    unsigned avu = *(const unsigned*)(aggb + (((size_t)b * cNP + n0 + row) * cF + lane * 2));
    float ci_ = sm.cinv[row];
    float a0 = bf2f((u16)(avu & 0xffffu)) * ci_;
    float a1 = bf2f((u16)(avu >> 16)) * ci_;
    *(unsigned*)(sm.bufP + (size_t)row * SP + lane * 2) = pack2(pv.x, pv.y);
    *(unsigned*)(sm.bufX + (size_t)row * SP + lane * 2) = pack2(a0, a1);
  }
  __syncthreads();  // b2

  f32x4 acc[4][2];

  // ---- pnode L1: K=256 over [pf|mean] ----
  init_acc_s(acc, w.bp1, cw, l16);
  kloop128s(sm.bufP, wb + (size_t)G8_Wp1 * 1024, acc, cw, l16, quad);
  kloop128s(sm.bufX, wb + (size_t)(G8_Wp1 + 16) * 1024, acc, cw, l16, quad);
  __syncthreads();  // b3: all waves done reading bufX(mean)
  store_s<true>(sm.bufX, acc, cw, l16, quad);  // h1
  __syncthreads();  // b4

  // ---- pnode L2 + cond-norm(set2) + residual -> bufP ----
  init_acc_s(acc, w.bp2, cw, l16);
  kloop128s(sm.bufX, wb + (size_t)G8_Wp2 * 1024, acc, cw, l16, quad);
  cond_norm_s(acc, sm.red, sm.musig, ss + (size_t)(2 * cB + b) * 256, cw, l16, quad, wv, t);
#pragma unroll
  for (int ri = 0; ri < 4; ++ri)
#pragma unroll
    for (int reg = 0; reg < 4; ++reg) {
      int row = ri * 16 + quad * 4 + reg;
#pragma unroll
      for (int ci = 0; ci < 2; ++ci)
        acc[ri][ci][reg] += bf2f(sm.bufP[(size_t)row * SP + cw + ci * 16 + l16]);
    }
  __syncthreads();  // b5: all waves done residual-reading bufP
  store_s<false>(sm.bufP, acc, cw, l16, quad);  // p_new
  __syncthreads();  // b6

  // ---- output L1: K=128 -> bufX ----
  init_acc_s(acc, w.bo1, cw, l16);
  kloop128s(sm.bufP, wb + (size_t)G8_Wo1 * 1024, acc, cw, l16, quad);
  store_s<true>(sm.bufX, acc, cw, l16, quad);  // bufX reads ended before cond-norm barriers
  __syncthreads();  // b7

  // ---- output L2 via MFMA: K=128, N=16 (4 used); wave wv owns rows wv*16..+15 ----
  {
    const u16* wo2 = wb + (size_t)G8_TOT * 1024;
    float bv = (l16 < 4) ? w.bo2[l16] : 0.0f;
    f32x4 a1 = {bv, bv, bv, bv};
#pragma unroll
    for (int k0 = 0; k0 < 4; ++k0) {
      s8v af = *(const s8v*)(sm.bufX + (size_t)(wv * 16 + l16) * SP + k0 * 32 + quad * 8);
      s8v bf = *(const s8v*)(wo2 + ((size_t)(k0 * 4 + quad) * 16 + l16) * 8);
      a1 = __builtin_amdgcn_mfma_f32_16x16x32_bf16(af, bf, a1, 0, 0, 0);
    }
    if (l16 < 4) {
      size_t obase = (size_t)b * cNP + n0 + wv * 16 + quad * 4;
#pragma unroll
      for (int reg = 0; reg < 4; ++reg)
        out[(obase + reg) * 4 + l16] = a1[reg];
    }
  }
}

// ---------------- launch ----------------
extern "C" void kernel_launch(void* const* d_in, const int* in_sizes, int n_in,
                              void* d_out, int out_size, void* d_ws, size_t ws_size,
                              hipStream_t stream) {
  const float* rnode = (const float*)d_in[0];
  const float* pnode = (const float*)d_in[1];
  const float* efeat = (const float*)d_in[2];
  const float* tau   = (const float*)d_in[3];
  const int* senders   = (const int*)d_in[40];
  const int* receivers = (const int*)d_in[41];
  float* ws = (float*)d_ws;
  u16* aggb = (u16*)d_ws;                 // bf16 [B][NP][128]
  u16* wb   = (u16*)(ws + WS_WB);
  u16* rnb  = (u16*)(ws + WS_RB);         // bf16 rnode copy

  SwzSrc sw;
  sw.p[0] = (const float*)d_in[5];   // We2
  sw.p[1] = (const float*)d_in[12];  // Wu1
  sw.p[2] = (const float*)d_in[13];  // Wu2
  sw.p[3] = (const float*)d_in[20];  // Wp1
  sw.p[4] = (const float*)d_in[21];  // Wp2
  sw.p[5] = (const float*)d_in[36];  // Wo1
  swz_kernel<<<(SWZ_N + 255) / 256, 256, 0, stream>>>(sw, (const float*)d_in[37], wb);

  const int nrn2 = (int)((size_t)cB * cNR * cF / 2);
  cvtn_kernel<<<(nrn2 + 255) / 256, 256, 0, stream>>>(rnode, rnb, nrn2);

  cond_kernel<<<dim3(3, cB), 256, 0, stream>>>(
      tau,
      (const float*)d_in[8],  (const float*)d_in[10],
      (const float*)d_in[9],  (const float*)d_in[11],
      (const float*)d_in[16], (const float*)d_in[18],
      (const float*)d_in[17], (const float*)d_in[19],
      (const float*)d_in[24], (const float*)d_in[26],
      (const float*)d_in[25], (const float*)d_in[27],
      ws + WS_SS);

  EWb ew = { (const float*)d_in[4], (const float*)d_in[6], (const float*)d_in[7],
             (const float*)d_in[14], (const float*)d_in[15] };   // We1, be1, be2, bu1, bu2
  PWb pw = { (const float*)d_in[22], (const float*)d_in[23], (const float*)d_in[38],
             (const float*)d_in[39] };                            // bp1, bp2, bo1, bo2

  const int n4 = (int)(WS_SS / 4);
  zero_kernel<<<(n4 + 255) / 256, 256, 0, stream>>>((float4*)ws, n4);

  edge_mfma<<<dim3(cE / 64, cB), 256, 0, stream>>>(
      rnb, pnode, efeat, senders, receivers, ew, wb,
      ws + WS_SS, aggb, ws + WS_CNT);

  pnode_mfma<<<dim3(cNP / 64, cB), 256, 0, stream>>>(
      pnode, pw, wb, ws + WS_SS, aggb, ws + WS_CNT,
      (float*)d_out);
}